// Round 1
// baseline (1597.612 us; speedup 1.0000x reference)
//
#include <hip/hip_runtime.h>
#include <math.h>

#define NB 64          // graphs
#define N0 1024        // nodes per graph (stage 1)
#define NEDGE 1048576  // total edges
#define FIN 10
#define HD 128
#define NCLS 10
#define KP1 205
#define KP2 41
#define KP3 9

static inline int ceil_div(int a, int b) { return (a + b - 1) / b; }

// ---------------- edge init / update ----------------
__global__ void init_edges_k(const int* __restrict__ ei, int* __restrict__ srcb,
                             int* __restrict__ dstb, int* __restrict__ em) {
    int e = blockIdx.x * blockDim.x + threadIdx.x;
    if (e >= NEDGE) return;
    srcb[e] = ei[e];
    dstb[e] = ei[NEDGE + e];
    em[e] = 1;
}

__global__ void edge_update_k(int* __restrict__ srcb, int* __restrict__ dstb,
                              int* __restrict__ em, const int* __restrict__ newid) {
    int e = blockIdx.x * blockDim.x + threadIdx.x;
    if (e >= NEDGE) return;
    int m = em[e];
    int ns = 0, nd = 0;
    if (m) {
        ns = newid[srcb[e]];
        nd = newid[dstb[e]];
        if (ns < 0 || nd < 0) { m = 0; ns = 0; nd = 0; }
    }
    srcb[e] = ns; dstb[e] = nd; em[e] = m;
}

// ---------------- degree / norm ----------------
__global__ void deg_k(const int* __restrict__ dstb, const int* __restrict__ em,
                      float* __restrict__ deg) {
    int e = blockIdx.x * blockDim.x + threadIdx.x;
    if (e >= NEDGE) return;
    if (em[e]) atomicAdd(&deg[dstb[e]], 1.0f);
}

__global__ void dis_k(const float* __restrict__ deg, float* __restrict__ dis, int n) {
    int i = blockIdx.x * blockDim.x + threadIdx.x;
    if (i >= n) return;
    dis[i] = 1.0f / sqrtf(deg[i] + 1.0f);
}

// ---------------- GEMM: C[n,128] = A[n,HI] @ W[HI,128] ----------------
template <int HI>
__global__ void gemm_n128_k(const float* __restrict__ A, const float* __restrict__ W,
                            float* __restrict__ C, int n) {
    __shared__ float Ws[64 * 128];  // 32KB chunk of W
    int t = blockIdx.x * blockDim.x + threadIdx.x;
    int row = t >> 7, col = t & 127;
    float acc = 0.f;
    for (int k0 = 0; k0 < HI; k0 += 64) {
        int kc = (HI - k0) < 64 ? (HI - k0) : 64;
        __syncthreads();
        for (int i = threadIdx.x; i < kc * 128; i += blockDim.x) Ws[i] = W[k0 * 128 + i];
        __syncthreads();
        if (row < n) {
            const float* a = A + (size_t)row * HI + k0;
            #pragma unroll 8
            for (int i = 0; i < kc; ++i) acc += a[i] * Ws[i * 128 + col];
        }
    }
    if (row < n) C[(size_t)row * 128 + col] = acc;
}

// ---------------- GEMV: out[n] = A[n,128] @ w[128] ----------------
__global__ void gemv128_k(const float* __restrict__ A, const float* __restrict__ w,
                          float* __restrict__ out, int n) {
    __shared__ float ws[128];
    for (int i = threadIdx.x; i < 128; i += blockDim.x) ws[i] = w[i];
    __syncthreads();
    int r = blockIdx.x * blockDim.x + threadIdx.x;
    if (r >= n) return;
    const float* a = A + (size_t)r * 128;
    float acc = 0.f;
    #pragma unroll 16
    for (int i = 0; i < 128; ++i) acc += a[i] * ws[i];
    out[r] = acc;
}

// ---------------- edge aggregation (128 features, atomic) ----------------
__global__ void aggregate128_k(const float* __restrict__ hW, const int* __restrict__ srcb,
                               const int* __restrict__ dstb, const int* __restrict__ em,
                               const float* __restrict__ dis, float* __restrict__ agg) {
    int t = blockIdx.x * blockDim.x + threadIdx.x;
    int e = t >> 6;  // 64 threads per edge, 2 feats each
    if (e >= NEDGE) return;
    if (!em[e]) return;
    int s = srcb[e], d = dstb[e];
    float nrm = dis[s] * dis[d];
    int f = (t & 63) * 2;
    atomicAdd(&agg[(size_t)d * 128 + f],     hW[(size_t)s * 128 + f] * nrm);
    atomicAdd(&agg[(size_t)d * 128 + f + 1], hW[(size_t)s * 128 + f + 1] * nrm);
}

__global__ void aggregate1_k(const float* __restrict__ hs, const int* __restrict__ srcb,
                             const int* __restrict__ dstb, const int* __restrict__ em,
                             const float* __restrict__ dis, float* __restrict__ sagg) {
    int e = blockIdx.x * blockDim.x + threadIdx.x;
    if (e >= NEDGE) return;
    if (!em[e]) return;
    int s = srcb[e], d = dstb[e];
    atomicAdd(&sagg[d], hs[s] * dis[s] * dis[d]);
}

// ---------------- finalize: out = agg + hW*dis^2 + b (relu) ----------------
__global__ void finalize128_relu_k(float* __restrict__ agg, const float* __restrict__ hW,
                                   const float* __restrict__ dis, const float* __restrict__ bias,
                                   int n) {
    int t = blockIdx.x * blockDim.x + threadIdx.x;
    if (t >= n * 128) return;
    int i = t >> 7, f = t & 127;
    float d2 = dis[i] * dis[i];
    float v = agg[t] + hW[t] * d2 + bias[f];
    agg[t] = fmaxf(v, 0.f);
}

__global__ void finalize1_k(float* __restrict__ score, const float* __restrict__ sagg,
                            const float* __restrict__ hs, const float* __restrict__ dis,
                            const float* __restrict__ bs, int n) {
    int i = blockIdx.x * blockDim.x + threadIdx.x;
    if (i >= n) return;
    float d2 = dis[i] * dis[i];
    score[i] = sagg[i] + hs[i] * d2 + bs[0];
}

// ---------------- per-graph top-k via bitonic sort in LDS ----------------
template <int CAP>
__global__ void topk_k(const float* __restrict__ score, int cur, int k, int* __restrict__ perm) {
    __shared__ float v[CAP];
    __shared__ int ix[CAP];
    int b = blockIdx.x;
    for (int i = threadIdx.x; i < CAP; i += blockDim.x) {
        v[i] = (i < cur) ? score[b * cur + i] : -INFINITY;
        ix[i] = i;
    }
    __syncthreads();
    for (int size = 2; size <= CAP; size <<= 1) {
        for (int stride = size >> 1; stride > 0; stride >>= 1) {
            for (int i = threadIdx.x; i < CAP / 2; i += blockDim.x) {
                int pos = 2 * i - (i & (stride - 1));
                int j = pos + stride;
                bool asc = (pos & size) == 0;
                float v0 = v[pos], v1 = v[j];
                int i0 = ix[pos], i1 = ix[j];
                // "j before pos" in (value desc, idx asc) order
                bool jb = (v1 > v0) || (v1 == v0 && i1 < i0);
                bool sw = asc ? jb : !jb;
                if (sw) { v[pos] = v1; v[j] = v0; ix[pos] = i1; ix[j] = i0; }
            }
            __syncthreads();
        }
    }
    for (int j = threadIdx.x; j < k; j += blockDim.x)
        perm[b * k + j] = b * cur + ix[j];
}

__global__ void scatter_newid_k(const int* __restrict__ perm, int* __restrict__ newid, int nk) {
    int i = blockIdx.x * blockDim.x + threadIdx.x;
    if (i < nk) newid[perm[i]] = i;
}

__global__ void pool_gather_k(const float* __restrict__ hout, const float* __restrict__ score,
                              const int* __restrict__ perm, float* __restrict__ hA, int nk) {
    int t = blockIdx.x * blockDim.x + threadIdx.x;
    if (t >= nk * 128) return;
    int i = t >> 7, f = t & 127;
    int p = perm[i];
    hA[t] = hout[(size_t)p * 128 + f] * tanhf(score[p]);
}

// ---------------- readout: z[b] += concat(max_j, mean_j) ----------------
__global__ void readout_add_k(const float* __restrict__ x, float* __restrict__ z, int k) {
    int b = blockIdx.x, f = threadIdx.x;  // 128 threads
    const float* p = x + (size_t)b * k * 128 + f;
    float m = -INFINITY, s = 0.f;
    for (int j = 0; j < k; ++j) {
        float vv = p[(size_t)j * 128];
        m = fmaxf(m, vv);
        s += vv;
    }
    z[b * 256 + f] += m;
    z[b * 256 + 128 + f] += s / (float)k;
}

// ---------------- MLP head + log_softmax ----------------
__global__ void mlp_head_k(const float* __restrict__ z,
                           const float* __restrict__ Wl1, const float* __restrict__ bl1,
                           const float* __restrict__ Wl2, const float* __restrict__ bl2,
                           const float* __restrict__ Wl3, const float* __restrict__ bl3,
                           float* __restrict__ out) {
    __shared__ float zr[256], h1[128], h2[64], lg[NCLS], red[2];
    int b = blockIdx.x, t = threadIdx.x;  // 128 threads
    zr[t] = z[b * 256 + t];
    zr[t + 128] = z[b * 256 + 128 + t];
    __syncthreads();
    float acc = bl1[t];
    #pragma unroll 8
    for (int i = 0; i < 256; ++i) acc += zr[i] * Wl1[i * 128 + t];
    h1[t] = fmaxf(acc, 0.f);
    __syncthreads();
    if (t < 64) {
        float a2 = bl2[t];
        #pragma unroll 8
        for (int i = 0; i < 128; ++i) a2 += h1[i] * Wl2[i * 64 + t];
        h2[t] = fmaxf(a2, 0.f);
    }
    __syncthreads();
    if (t < NCLS) {
        float a3 = bl3[t];
        #pragma unroll 8
        for (int i = 0; i < 64; ++i) a3 += h2[i] * Wl3[i * NCLS + t];
        lg[t] = a3;
    }
    __syncthreads();
    if (t == 0) {
        float m = lg[0];
        for (int i = 1; i < NCLS; ++i) m = fmaxf(m, lg[i]);
        float s = 0.f;
        for (int i = 0; i < NCLS; ++i) s += expf(lg[i] - m);
        red[0] = m; red[1] = logf(s);
    }
    __syncthreads();
    if (t < NCLS) out[b * NCLS + t] = lg[t] - red[0] - red[1];
}

// ---------------- host ----------------
extern "C" void kernel_launch(void* const* d_in, const int* in_sizes, int n_in,
                              void* d_out, int out_size, void* d_ws, size_t ws_size,
                              hipStream_t stream) {
    const float* x   = (const float*)d_in[0];
    const int*   ei  = (const int*)d_in[1];
    const float* W1  = (const float*)d_in[2];  const float* b1  = (const float*)d_in[3];
    const float* W2  = (const float*)d_in[4];  const float* b2  = (const float*)d_in[5];
    const float* W3  = (const float*)d_in[6];  const float* b3  = (const float*)d_in[7];
    const float* Ws1 = (const float*)d_in[8];  const float* bs1 = (const float*)d_in[9];
    const float* Ws2 = (const float*)d_in[10]; const float* bs2 = (const float*)d_in[11];
    const float* Ws3 = (const float*)d_in[12]; const float* bs3 = (const float*)d_in[13];
    const float* Wl1 = (const float*)d_in[14]; const float* bl1 = (const float*)d_in[15];
    const float* Wl2 = (const float*)d_in[16]; const float* bl2 = (const float*)d_in[17];
    const float* Wl3 = (const float*)d_in[18]; const float* bl3 = (const float*)d_in[19];
    float* out = (float*)d_out;

    const int NMAX = NB * N0;  // 65536

    char* p = (char*)d_ws;
    float* hW    = (float*)p; p += (size_t)NMAX * 128 * 4;
    float* agg   = (float*)p; p += (size_t)NMAX * 128 * 4;
    float* hA    = (float*)p; p += (size_t)NB * KP1 * 128 * 4;
    float* deg   = (float*)p; p += (size_t)NMAX * 4;
    float* dis   = (float*)p; p += (size_t)NMAX * 4;
    float* hs    = (float*)p; p += (size_t)NMAX * 4;
    float* sagg  = (float*)p; p += (size_t)NMAX * 4;
    float* score = (float*)p; p += (size_t)NMAX * 4;
    float* z     = (float*)p; p += (size_t)NB * 256 * 4;
    int* perm    = (int*)p;   p += (size_t)NB * KP1 * 4;
    int* newid   = (int*)p;   p += (size_t)NMAX * 4;
    int* srcb    = (int*)p;   p += (size_t)NEDGE * 4;
    int* dstb    = (int*)p;   p += (size_t)NEDGE * 4;
    int* emaskb  = (int*)p;   p += (size_t)NEDGE * 4;

    const int EB = ceil_div(NEDGE, 256);

    init_edges_k<<<EB, 256, 0, stream>>>(ei, srcb, dstb, emaskb);
    hipMemsetAsync(z, 0, (size_t)NB * 256 * 4, stream);

    auto stage = [&](const float* Ain, int HI, int cur, int k,
                     const float* W, const float* bb,
                     const float* Wsc, const float* bsc) {
        int n = cur * NB;
        hipMemsetAsync(agg, 0, (size_t)n * 128 * 4, stream);
        hipMemsetAsync(deg, 0, (size_t)n * 4, stream);
        if (HI == FIN)
            gemm_n128_k<FIN><<<ceil_div(n * 128, 256), 256, 0, stream>>>(Ain, W, hW, n);
        else
            gemm_n128_k<128><<<ceil_div(n * 128, 256), 256, 0, stream>>>(Ain, W, hW, n);
        deg_k<<<EB, 256, 0, stream>>>(dstb, emaskb, deg);
        dis_k<<<ceil_div(n, 256), 256, 0, stream>>>(deg, dis, n);
        aggregate128_k<<<ceil_div(NEDGE * 64 / 256, 1), 256, 0, stream>>>(hW, srcb, dstb, emaskb, dis, agg);
        finalize128_relu_k<<<ceil_div(n * 128, 256), 256, 0, stream>>>(agg, hW, dis, bb, n);
        // score GCN (shares deg/dis with conv — same mask)
        gemv128_k<<<ceil_div(n, 256), 256, 0, stream>>>(agg, Wsc, hs, n);
        hipMemsetAsync(sagg, 0, (size_t)n * 4, stream);
        aggregate1_k<<<EB, 256, 0, stream>>>(hs, srcb, dstb, emaskb, dis, sagg);
        finalize1_k<<<ceil_div(n, 256), 256, 0, stream>>>(score, sagg, hs, dis, bsc, n);
        // top-k pooling
        if (cur == N0)       topk_k<1024><<<NB, 256, 0, stream>>>(score, cur, k, perm);
        else if (cur == KP1) topk_k<256><<<NB, 256, 0, stream>>>(score, cur, k, perm);
        else                 topk_k<64><<<NB, 256, 0, stream>>>(score, cur, k, perm);
        hipMemsetAsync(newid, 0xFF, (size_t)n * 4, stream);
        scatter_newid_k<<<ceil_div(NB * k, 256), 256, 0, stream>>>(perm, newid, NB * k);
        pool_gather_k<<<ceil_div(NB * k * 128, 256), 256, 0, stream>>>(agg, score, perm, hA, NB * k);
        readout_add_k<<<NB, 128, 0, stream>>>(hA, z, k);
        edge_update_k<<<EB, 256, 0, stream>>>(srcb, dstb, emaskb, newid);
    };

    stage(x,  FIN, N0,  KP1, W1, b1, Ws1, bs1);
    stage(hA, 128, KP1, KP2, W2, b2, Ws2, bs2);
    stage(hA, 128, KP2, KP3, W3, b3, Ws3, bs3);

    mlp_head_k<<<NB, 128, 0, stream>>>(z, Wl1, bl1, Wl2, bl2, Wl3, bl3, out);
}

// Round 2
// 1136.623 us; speedup vs baseline: 1.4056x; 1.4056x over previous
//
#include <hip/hip_runtime.h>
#include <math.h>

#define NB 64          // graphs
#define N0 1024        // nodes per graph (stage 1)
#define NEDGE 1048576  // total edges
#define FIN 10
#define HD 128
#define NCLS 10
#define KP1 205
#define KP2 41
#define KP3 9

static inline int ceil_div(int a, int b) { return (a + b - 1) / b; }

// ---------------- edge init / update ----------------
__global__ void init_edges_k(const int* __restrict__ ei, int* __restrict__ srcb,
                             int* __restrict__ dstb, int* __restrict__ em) {
    int e = blockIdx.x * blockDim.x + threadIdx.x;
    if (e >= NEDGE) return;
    srcb[e] = ei[e];
    dstb[e] = ei[NEDGE + e];
    em[e] = 1;
}

__global__ void edge_update_k(int* __restrict__ srcb, int* __restrict__ dstb,
                              int* __restrict__ em, const int* __restrict__ newid) {
    int e = blockIdx.x * blockDim.x + threadIdx.x;
    if (e >= NEDGE) return;
    int m = em[e];
    int ns = 0, nd = 0;
    if (m) {
        ns = newid[srcb[e]];
        nd = newid[dstb[e]];
        if (ns < 0 || nd < 0) { m = 0; ns = 0; nd = 0; }
    }
    srcb[e] = ns; dstb[e] = nd; em[e] = m;
}

// ---------------- CSR build: count -> scan(+dis,cursor) -> scatter ----------------
__global__ void count_k(const int* __restrict__ dstb, const int* __restrict__ em,
                        int* __restrict__ cnt) {
    int e = blockIdx.x * blockDim.x + threadIdx.x;
    if (e >= NEDGE) return;
    if (em[e]) atomicAdd(&cnt[dstb[e]], 1);
}

// single-block chained exclusive scan over cnt[0..n), also emits cursor copy and dis
__global__ void scan_dis_k(const int* __restrict__ cnt, int* __restrict__ off,
                           int* __restrict__ cursor, float* __restrict__ dis, int n) {
    __shared__ int buf[256];
    __shared__ int carry;
    if (threadIdx.x == 0) carry = 0;
    __syncthreads();
    for (int base = 0; base < n; base += 256) {
        int i = base + threadIdx.x;
        int v = (i < n) ? cnt[i] : 0;
        buf[threadIdx.x] = v;
        __syncthreads();
        #pragma unroll
        for (int s = 1; s < 256; s <<= 1) {
            int t = (threadIdx.x >= s) ? buf[threadIdx.x - s] : 0;
            __syncthreads();
            buf[threadIdx.x] += t;
            __syncthreads();
        }
        if (i < n) {
            int excl = carry + buf[threadIdx.x] - v;
            off[i] = excl;
            cursor[i] = excl;
            dis[i] = rsqrtf((float)v + 1.0f);
        }
        __syncthreads();
        if (threadIdx.x == 255) carry += buf[255];
        __syncthreads();
    }
}

__global__ void scatter_k(const int* __restrict__ srcb, const int* __restrict__ dstb,
                          const int* __restrict__ em, int* __restrict__ cursor,
                          int* __restrict__ csr_src) {
    int e = blockIdx.x * blockDim.x + threadIdx.x;
    if (e >= NEDGE) return;
    if (!em[e]) return;
    int p = atomicAdd(&cursor[dstb[e]], 1);
    csr_src[p] = srcb[e];
}

// ---------------- GEMM: C[n,128] = A[n,HI] @ W[HI,128] ----------------
template <int HI>
__global__ void gemm_n128_k(const float* __restrict__ A, const float* __restrict__ W,
                            float* __restrict__ C, int n) {
    __shared__ float Ws[64 * 128];  // 32KB chunk of W
    int t = blockIdx.x * blockDim.x + threadIdx.x;
    int row = t >> 7, col = t & 127;
    float acc = 0.f;
    for (int k0 = 0; k0 < HI; k0 += 64) {
        int kc = (HI - k0) < 64 ? (HI - k0) : 64;
        __syncthreads();
        for (int i = threadIdx.x; i < kc * 128; i += blockDim.x) Ws[i] = W[k0 * 128 + i];
        __syncthreads();
        if (row < n) {
            const float* a = A + (size_t)row * HI + k0;
            #pragma unroll 8
            for (int i = 0; i < kc; ++i) acc += a[i] * Ws[i * 128 + col];
        }
    }
    if (row < n) C[(size_t)row * 128 + col] = acc;
}

// ---------------- GEMV: out[n] = A[n,128] @ w[128] ----------------
__global__ void gemv128_k(const float* __restrict__ A, const float* __restrict__ w,
                          float* __restrict__ out, int n) {
    __shared__ float ws[128];
    for (int i = threadIdx.x; i < 128; i += blockDim.x) ws[i] = w[i];
    __syncthreads();
    int r = blockIdx.x * blockDim.x + threadIdx.x;
    if (r >= n) return;
    const float* a = A + (size_t)r * 128;
    float acc = 0.f;
    #pragma unroll 16
    for (int i = 0; i < 128; ++i) acc += a[i] * ws[i];
    out[r] = acc;
}

// ---------------- fused GCN aggregation (CSR gather) + self-loop + bias (+relu) ----
// out[i][f] = relu( dis[i] * sum_j hW[src_j][f]*dis[src_j] + hW[i][f]*dis[i]^2 + b[f] )
__global__ void gcn_agg_fused_k(const float* __restrict__ hW, const int* __restrict__ csr_src,
                                const int* __restrict__ off, const int* __restrict__ cnt,
                                const float* __restrict__ dis, const float* __restrict__ bias,
                                float* __restrict__ hout, int n) {
    int t = blockIdx.x * blockDim.x + threadIdx.x;
    int i = t >> 7, f = t & 127;
    if (i >= n) return;
    int s0 = off[i], e0 = s0 + cnt[i];
    float acc = 0.f;
    for (int j = s0; j < e0; ++j) {
        int s = csr_src[j];
        acc += hW[(size_t)s * 128 + f] * dis[s];
    }
    float di = dis[i];
    float v = di * acc + hW[(size_t)i * 128 + f] * (di * di) + bias[f];
    hout[(size_t)i * 128 + f] = fmaxf(v, 0.f);
}

// score[i] = dis[i] * sum_j hs[src_j]*dis[src_j] + hs[i]*dis[i]^2 + bs
__global__ void score_fused_k(const float* __restrict__ hs, const int* __restrict__ csr_src,
                              const int* __restrict__ off, const int* __restrict__ cnt,
                              const float* __restrict__ dis, const float* __restrict__ bs,
                              float* __restrict__ score, int n) {
    int i = blockIdx.x * blockDim.x + threadIdx.x;
    if (i >= n) return;
    int s0 = off[i], e0 = s0 + cnt[i];
    float acc = 0.f;
    for (int j = s0; j < e0; ++j) {
        int s = csr_src[j];
        acc += hs[s] * dis[s];
    }
    float di = dis[i];
    score[i] = di * acc + hs[i] * (di * di) + bs[0];
}

// ---------------- per-graph top-k via bitonic sort in LDS ----------------
template <int CAP>
__global__ void topk_k(const float* __restrict__ score, int cur, int k, int* __restrict__ perm) {
    __shared__ float v[CAP];
    __shared__ int ix[CAP];
    int b = blockIdx.x;
    for (int i = threadIdx.x; i < CAP; i += blockDim.x) {
        v[i] = (i < cur) ? score[b * cur + i] : -INFINITY;
        ix[i] = i;
    }
    __syncthreads();
    for (int size = 2; size <= CAP; size <<= 1) {
        for (int stride = size >> 1; stride > 0; stride >>= 1) {
            for (int i = threadIdx.x; i < CAP / 2; i += blockDim.x) {
                int pos = 2 * i - (i & (stride - 1));
                int j = pos + stride;
                bool asc = (pos & size) == 0;
                float v0 = v[pos], v1 = v[j];
                int i0 = ix[pos], i1 = ix[j];
                bool jb = (v1 > v0) || (v1 == v0 && i1 < i0);  // j-before-pos in (desc, idx asc)
                bool sw = asc ? jb : !jb;
                if (sw) { v[pos] = v1; v[j] = v0; ix[pos] = i1; ix[j] = i0; }
            }
            __syncthreads();
        }
    }
    for (int j = threadIdx.x; j < k; j += blockDim.x)
        perm[b * k + j] = b * cur + ix[j];
}

__global__ void scatter_newid_k(const int* __restrict__ perm, int* __restrict__ newid, int nk) {
    int i = blockIdx.x * blockDim.x + threadIdx.x;
    if (i < nk) newid[perm[i]] = i;
}

__global__ void pool_gather_k(const float* __restrict__ hout, const float* __restrict__ score,
                              const int* __restrict__ perm, float* __restrict__ hA, int nk) {
    int t = blockIdx.x * blockDim.x + threadIdx.x;
    if (t >= nk * 128) return;
    int i = t >> 7, f = t & 127;
    int p = perm[i];
    hA[t] = hout[(size_t)p * 128 + f] * tanhf(score[p]);
}

// ---------------- readout: z[b] += concat(max_j, mean_j) ----------------
__global__ void readout_add_k(const float* __restrict__ x, float* __restrict__ z, int k) {
    int b = blockIdx.x, f = threadIdx.x;  // 128 threads
    const float* p = x + (size_t)b * k * 128 + f;
    float m = -INFINITY, s = 0.f;
    for (int j = 0; j < k; ++j) {
        float vv = p[(size_t)j * 128];
        m = fmaxf(m, vv);
        s += vv;
    }
    z[b * 256 + f] += m;
    z[b * 256 + 128 + f] += s / (float)k;
}

// ---------------- MLP head + log_softmax ----------------
__global__ void mlp_head_k(const float* __restrict__ z,
                           const float* __restrict__ Wl1, const float* __restrict__ bl1,
                           const float* __restrict__ Wl2, const float* __restrict__ bl2,
                           const float* __restrict__ Wl3, const float* __restrict__ bl3,
                           float* __restrict__ out) {
    __shared__ float zr[256], h1[128], h2[64], lg[NCLS], red[2];
    int b = blockIdx.x, t = threadIdx.x;  // 128 threads
    zr[t] = z[b * 256 + t];
    zr[t + 128] = z[b * 256 + 128 + t];
    __syncthreads();
    float acc = bl1[t];
    #pragma unroll 8
    for (int i = 0; i < 256; ++i) acc += zr[i] * Wl1[i * 128 + t];
    h1[t] = fmaxf(acc, 0.f);
    __syncthreads();
    if (t < 64) {
        float a2 = bl2[t];
        #pragma unroll 8
        for (int i = 0; i < 128; ++i) a2 += h1[i] * Wl2[i * 64 + t];
        h2[t] = fmaxf(a2, 0.f);
    }
    __syncthreads();
    if (t < NCLS) {
        float a3 = bl3[t];
        #pragma unroll 8
        for (int i = 0; i < 64; ++i) a3 += h2[i] * Wl3[i * NCLS + t];
        lg[t] = a3;
    }
    __syncthreads();
    if (t == 0) {
        float m = lg[0];
        for (int i = 1; i < NCLS; ++i) m = fmaxf(m, lg[i]);
        float s = 0.f;
        for (int i = 0; i < NCLS; ++i) s += expf(lg[i] - m);
        red[0] = m; red[1] = logf(s);
    }
    __syncthreads();
    if (t < NCLS) out[b * NCLS + t] = lg[t] - red[0] - red[1];
}

// ---------------- host ----------------
extern "C" void kernel_launch(void* const* d_in, const int* in_sizes, int n_in,
                              void* d_out, int out_size, void* d_ws, size_t ws_size,
                              hipStream_t stream) {
    const float* x   = (const float*)d_in[0];
    const int*   ei  = (const int*)d_in[1];
    const float* W1  = (const float*)d_in[2];  const float* b1  = (const float*)d_in[3];
    const float* W2  = (const float*)d_in[4];  const float* b2  = (const float*)d_in[5];
    const float* W3  = (const float*)d_in[6];  const float* b3  = (const float*)d_in[7];
    const float* Ws1 = (const float*)d_in[8];  const float* bs1 = (const float*)d_in[9];
    const float* Ws2 = (const float*)d_in[10]; const float* bs2 = (const float*)d_in[11];
    const float* Ws3 = (const float*)d_in[12]; const float* bs3 = (const float*)d_in[13];
    const float* Wl1 = (const float*)d_in[14]; const float* bl1 = (const float*)d_in[15];
    const float* Wl2 = (const float*)d_in[16]; const float* bl2 = (const float*)d_in[17];
    const float* Wl3 = (const float*)d_in[18]; const float* bl3 = (const float*)d_in[19];
    float* out = (float*)d_out;

    const int NMAX = NB * N0;  // 65536

    char* p = (char*)d_ws;
    float* hW     = (float*)p; p += (size_t)NMAX * 128 * 4;
    float* hout   = (float*)p; p += (size_t)NMAX * 128 * 4;
    float* hA     = (float*)p; p += (size_t)NB * KP1 * 128 * 4;
    float* dis    = (float*)p; p += (size_t)NMAX * 4;
    float* hs     = (float*)p; p += (size_t)NMAX * 4;
    float* score  = (float*)p; p += (size_t)NMAX * 4;
    float* z      = (float*)p; p += (size_t)NB * 256 * 4;
    int* perm     = (int*)p;   p += (size_t)NB * KP1 * 4;
    int* newid    = (int*)p;   p += (size_t)NMAX * 4;
    int* srcb     = (int*)p;   p += (size_t)NEDGE * 4;
    int* dstb     = (int*)p;   p += (size_t)NEDGE * 4;
    int* emaskb   = (int*)p;   p += (size_t)NEDGE * 4;
    int* cnt      = (int*)p;   p += (size_t)NMAX * 4;
    int* off      = (int*)p;   p += (size_t)NMAX * 4;
    int* cursor   = (int*)p;   p += (size_t)NMAX * 4;
    int* csr_src  = (int*)p;   p += (size_t)NEDGE * 4;

    const int EB = ceil_div(NEDGE, 256);

    init_edges_k<<<EB, 256, 0, stream>>>(ei, srcb, dstb, emaskb);
    hipMemsetAsync(z, 0, (size_t)NB * 256 * 4, stream);

    auto stage = [&](const float* Ain, int HI, int cur, int k,
                     const float* W, const float* bb,
                     const float* Wsc, const float* bsc) {
        int n = cur * NB;
        // CSR build (also yields deg -> dis)
        hipMemsetAsync(cnt, 0, (size_t)n * 4, stream);
        if (HI == FIN)
            gemm_n128_k<FIN><<<ceil_div(n * 128, 256), 256, 0, stream>>>(Ain, W, hW, n);
        else
            gemm_n128_k<128><<<ceil_div(n * 128, 256), 256, 0, stream>>>(Ain, W, hW, n);
        count_k<<<EB, 256, 0, stream>>>(dstb, emaskb, cnt);
        scan_dis_k<<<1, 256, 0, stream>>>(cnt, off, cursor, dis, n);
        scatter_k<<<EB, 256, 0, stream>>>(srcb, dstb, emaskb, cursor, csr_src);
        // fused GCN conv (+relu)
        gcn_agg_fused_k<<<ceil_div(n * 128, 256), 256, 0, stream>>>(hW, csr_src, off, cnt, dis, bb, hout, n);
        // score GCN (shares CSR/dis — same mask)
        gemv128_k<<<ceil_div(n, 256), 256, 0, stream>>>(hout, Wsc, hs, n);
        score_fused_k<<<ceil_div(n, 256), 256, 0, stream>>>(hs, csr_src, off, cnt, dis, bsc, score, n);
        // top-k pooling
        if (cur == N0)       topk_k<1024><<<NB, 256, 0, stream>>>(score, cur, k, perm);
        else if (cur == KP1) topk_k<256><<<NB, 256, 0, stream>>>(score, cur, k, perm);
        else                 topk_k<64><<<NB, 256, 0, stream>>>(score, cur, k, perm);
        hipMemsetAsync(newid, 0xFF, (size_t)n * 4, stream);
        scatter_newid_k<<<ceil_div(NB * k, 256), 256, 0, stream>>>(perm, newid, NB * k);
        pool_gather_k<<<ceil_div(NB * k * 128, 256), 256, 0, stream>>>(hout, score, perm, hA, NB * k);
        readout_add_k<<<NB, 128, 0, stream>>>(hA, z, k);
        edge_update_k<<<EB, 256, 0, stream>>>(srcb, dstb, emaskb, newid);
    };

    stage(x,  FIN, N0,  KP1, W1, b1, Ws1, bs1);
    stage(hA, 128, KP1, KP2, W2, b2, Ws2, bs2);
    stage(hA, 128, KP2, KP3, W3, b3, Ws3, bs3);

    mlp_head_k<<<NB, 128, 0, stream>>>(z, Wl1, bl1, Wl2, bl2, Wl3, bl3, out);
}

// Round 3
// 783.306 us; speedup vs baseline: 2.0396x; 1.4511x over previous
//
#include <hip/hip_runtime.h>
#include <math.h>

#define NB 64          // graphs
#define N0 1024        // nodes per graph (stage 1)
#define NEDGE 1048576  // total edges
#define FIN 10
#define HD 128
#define NCLS 10
#define KP1 205
#define KP2 41
#define KP3 9

static inline int ceil_div(int a, int b) { return (a + b - 1) / b; }

// ---------------- edge init / update ----------------
__global__ void init_edges_k(const int* __restrict__ ei, int* __restrict__ srcb,
                             int* __restrict__ dstb, int* __restrict__ em) {
    int e = blockIdx.x * blockDim.x + threadIdx.x;
    if (e >= NEDGE) return;
    srcb[e] = ei[e];
    dstb[e] = ei[NEDGE + e];
    em[e] = 1;
}

__global__ void edge_update_k(int* __restrict__ srcb, int* __restrict__ dstb,
                              int* __restrict__ em, const int* __restrict__ newid) {
    int e = blockIdx.x * blockDim.x + threadIdx.x;
    if (e >= NEDGE) return;
    int m = em[e];
    int ns = 0, nd = 0;
    if (m) {
        ns = newid[srcb[e]];
        nd = newid[dstb[e]];
        if (ns < 0 || nd < 0) { m = 0; ns = 0; nd = 0; }
    }
    srcb[e] = ns; dstb[e] = nd; em[e] = m;
}

// ---------------- CSR build: count -> offsets(+dis,cursor) -> scatter ----------------
__global__ void count_k(const int* __restrict__ dstb, const int* __restrict__ em,
                        int* __restrict__ cnt) {
    int e = blockIdx.x * blockDim.x + threadIdx.x;
    if (e >= NEDGE) return;
    if (em[e]) atomicAdd(&cnt[dstb[e]], 1);
}

// Parallel region assignment: per-block LDS scan + one atomicAdd for the block base.
// Region ORDER across nodes is arbitrary — only disjointness matters for the gather.
__global__ void offsets_k(const int* __restrict__ cnt, int* __restrict__ off,
                          int* __restrict__ cursor, float* __restrict__ dis,
                          int* __restrict__ gctr, int n) {
    __shared__ int buf[256];
    __shared__ int base;
    int i = blockIdx.x * 256 + threadIdx.x;
    int v = (i < n) ? cnt[i] : 0;
    buf[threadIdx.x] = v;
    __syncthreads();
    #pragma unroll
    for (int s = 1; s < 256; s <<= 1) {
        int t = (threadIdx.x >= s) ? buf[threadIdx.x - s] : 0;
        __syncthreads();
        buf[threadIdx.x] += t;
        __syncthreads();
    }
    if (threadIdx.x == 255) base = atomicAdd(gctr, buf[255]);
    __syncthreads();
    if (i < n) {
        int excl = base + buf[threadIdx.x] - v;
        off[i] = excl;
        cursor[i] = excl;
        dis[i] = rsqrtf((float)v + 1.0f);
    }
}

__global__ void scatter_k(const int* __restrict__ srcb, const int* __restrict__ dstb,
                          const int* __restrict__ em, int* __restrict__ cursor,
                          int* __restrict__ csr_src) {
    int e = blockIdx.x * blockDim.x + threadIdx.x;
    if (e >= NEDGE) return;
    if (!em[e]) return;
    int p = atomicAdd(&cursor[dstb[e]], 1);
    csr_src[p] = srcb[e];
}

// ---------------- GEMM: C[n,128] = A[n,HI] @ W[HI,128] ----------------
template <int HI>
__global__ void gemm_n128_k(const float* __restrict__ A, const float* __restrict__ W,
                            float* __restrict__ C, int n) {
    __shared__ float Ws[64 * 128];  // 32KB chunk of W
    int t = blockIdx.x * blockDim.x + threadIdx.x;
    int row = t >> 7, col = t & 127;
    float acc = 0.f;
    for (int k0 = 0; k0 < HI; k0 += 64) {
        int kc = (HI - k0) < 64 ? (HI - k0) : 64;
        __syncthreads();
        for (int i = threadIdx.x; i < kc * 128; i += blockDim.x) Ws[i] = W[k0 * 128 + i];
        __syncthreads();
        if (row < n) {
            const float* a = A + (size_t)row * HI + k0;
            #pragma unroll 8
            for (int i = 0; i < kc; ++i) acc += a[i] * Ws[i * 128 + col];
        }
    }
    if (row < n) C[(size_t)row * 128 + col] = acc;
}

// ---------------- GEMV: out[n] = A[n,128] @ w[128] ----------------
__global__ void gemv128_k(const float* __restrict__ A, const float* __restrict__ w,
                          float* __restrict__ out, int n) {
    __shared__ float ws[128];
    for (int i = threadIdx.x; i < 128; i += blockDim.x) ws[i] = w[i];
    __syncthreads();
    int r = blockIdx.x * blockDim.x + threadIdx.x;
    if (r >= n) return;
    const float* a = A + (size_t)r * 128;
    float acc = 0.f;
    #pragma unroll 16
    for (int i = 0; i < 128; ++i) acc += a[i] * ws[i];
    out[r] = acc;
}

// ---------------- fused GCN aggregation (CSR gather) + self-loop + bias (+relu) ----
// out[i][f] = relu( dis[i] * sum_j hW[src_j][f]*dis[src_j] + hW[i][f]*dis[i]^2 + b[f] )
__global__ void gcn_agg_fused_k(const float* __restrict__ hW, const int* __restrict__ csr_src,
                                const int* __restrict__ off, const int* __restrict__ cnt,
                                const float* __restrict__ dis, const float* __restrict__ bias,
                                float* __restrict__ hout, int n) {
    int t = blockIdx.x * blockDim.x + threadIdx.x;
    int i = t >> 7, f = t & 127;
    if (i >= n) return;
    int s0 = off[i], e0 = s0 + cnt[i];
    float acc = 0.f;
    for (int j = s0; j < e0; ++j) {
        int s = csr_src[j];
        acc += hW[(size_t)s * 128 + f] * dis[s];
    }
    float di = dis[i];
    float v = di * acc + hW[(size_t)i * 128 + f] * (di * di) + bias[f];
    hout[(size_t)i * 128 + f] = fmaxf(v, 0.f);
}

// score[i] = dis[i] * sum_j hs[src_j]*dis[src_j] + hs[i]*dis[i]^2 + bs
__global__ void score_fused_k(const float* __restrict__ hs, const int* __restrict__ csr_src,
                              const int* __restrict__ off, const int* __restrict__ cnt,
                              const float* __restrict__ dis, const float* __restrict__ bs,
                              float* __restrict__ score, int n) {
    int i = blockIdx.x * blockDim.x + threadIdx.x;
    if (i >= n) return;
    int s0 = off[i], e0 = s0 + cnt[i];
    float acc = 0.f;
    for (int j = s0; j < e0; ++j) {
        int s = csr_src[j];
        acc += hs[s] * dis[s];
    }
    float di = dis[i];
    score[i] = di * acc + hs[i] * (di * di) + bs[0];
}

// ---------------- per-graph top-k via bitonic sort in LDS ----------------
template <int CAP>
__global__ void topk_k(const float* __restrict__ score, int cur, int k, int* __restrict__ perm) {
    __shared__ float v[CAP];
    __shared__ int ix[CAP];
    int b = blockIdx.x;
    for (int i = threadIdx.x; i < CAP; i += blockDim.x) {
        v[i] = (i < cur) ? score[b * cur + i] : -INFINITY;
        ix[i] = i;
    }
    __syncthreads();
    for (int size = 2; size <= CAP; size <<= 1) {
        for (int stride = size >> 1; stride > 0; stride >>= 1) {
            for (int i = threadIdx.x; i < CAP / 2; i += blockDim.x) {
                int pos = 2 * i - (i & (stride - 1));
                int j = pos + stride;
                bool asc = (pos & size) == 0;
                float v0 = v[pos], v1 = v[j];
                int i0 = ix[pos], i1 = ix[j];
                bool jb = (v1 > v0) || (v1 == v0 && i1 < i0);  // j-before-pos in (desc, idx asc)
                bool sw = asc ? jb : !jb;
                if (sw) { v[pos] = v1; v[j] = v0; ix[pos] = i1; ix[j] = i0; }
            }
            __syncthreads();
        }
    }
    for (int j = threadIdx.x; j < k; j += blockDim.x)
        perm[b * k + j] = b * cur + ix[j];
}

__global__ void scatter_newid_k(const int* __restrict__ perm, int* __restrict__ newid, int nk) {
    int i = blockIdx.x * blockDim.x + threadIdx.x;
    if (i < nk) newid[perm[i]] = i;
}

__global__ void pool_gather_k(const float* __restrict__ hout, const float* __restrict__ score,
                              const int* __restrict__ perm, float* __restrict__ hA, int nk) {
    int t = blockIdx.x * blockDim.x + threadIdx.x;
    if (t >= nk * 128) return;
    int i = t >> 7, f = t & 127;
    int p = perm[i];
    hA[t] = hout[(size_t)p * 128 + f] * tanhf(score[p]);
}

// ---------------- readout: z[b] += concat(max_j, mean_j) ----------------
__global__ void readout_add_k(const float* __restrict__ x, float* __restrict__ z, int k) {
    int b = blockIdx.x, f = threadIdx.x;  // 128 threads
    const float* p = x + (size_t)b * k * 128 + f;
    float m = -INFINITY, s = 0.f;
    for (int j = 0; j < k; ++j) {
        float vv = p[(size_t)j * 128];
        m = fmaxf(m, vv);
        s += vv;
    }
    z[b * 256 + f] += m;
    z[b * 256 + 128 + f] += s / (float)k;
}

// ---------------- MLP head + log_softmax ----------------
__global__ void mlp_head_k(const float* __restrict__ z,
                           const float* __restrict__ Wl1, const float* __restrict__ bl1,
                           const float* __restrict__ Wl2, const float* __restrict__ bl2,
                           const float* __restrict__ Wl3, const float* __restrict__ bl3,
                           float* __restrict__ out) {
    __shared__ float zr[256], h1[128], h2[64], lg[NCLS], red[2];
    int b = blockIdx.x, t = threadIdx.x;  // 128 threads
    zr[t] = z[b * 256 + t];
    zr[t + 128] = z[b * 256 + 128 + t];
    __syncthreads();
    float acc = bl1[t];
    #pragma unroll 8
    for (int i = 0; i < 256; ++i) acc += zr[i] * Wl1[i * 128 + t];
    h1[t] = fmaxf(acc, 0.f);
    __syncthreads();
    if (t < 64) {
        float a2 = bl2[t];
        #pragma unroll 8
        for (int i = 0; i < 128; ++i) a2 += h1[i] * Wl2[i * 64 + t];
        h2[t] = fmaxf(a2, 0.f);
    }
    __syncthreads();
    if (t < NCLS) {
        float a3 = bl3[t];
        #pragma unroll 8
        for (int i = 0; i < 64; ++i) a3 += h2[i] * Wl3[i * NCLS + t];
        lg[t] = a3;
    }
    __syncthreads();
    if (t == 0) {
        float m = lg[0];
        for (int i = 1; i < NCLS; ++i) m = fmaxf(m, lg[i]);
        float s = 0.f;
        for (int i = 0; i < NCLS; ++i) s += expf(lg[i] - m);
        red[0] = m; red[1] = logf(s);
    }
    __syncthreads();
    if (t < NCLS) out[b * NCLS + t] = lg[t] - red[0] - red[1];
}

// ---------------- host ----------------
extern "C" void kernel_launch(void* const* d_in, const int* in_sizes, int n_in,
                              void* d_out, int out_size, void* d_ws, size_t ws_size,
                              hipStream_t stream) {
    const float* x   = (const float*)d_in[0];
    const int*   ei  = (const int*)d_in[1];
    const float* W1  = (const float*)d_in[2];  const float* b1  = (const float*)d_in[3];
    const float* W2  = (const float*)d_in[4];  const float* b2  = (const float*)d_in[5];
    const float* W3  = (const float*)d_in[6];  const float* b3  = (const float*)d_in[7];
    const float* Ws1 = (const float*)d_in[8];  const float* bs1 = (const float*)d_in[9];
    const float* Ws2 = (const float*)d_in[10]; const float* bs2 = (const float*)d_in[11];
    const float* Ws3 = (const float*)d_in[12]; const float* bs3 = (const float*)d_in[13];
    const float* Wl1 = (const float*)d_in[14]; const float* bl1 = (const float*)d_in[15];
    const float* Wl2 = (const float*)d_in[16]; const float* bl2 = (const float*)d_in[17];
    const float* Wl3 = (const float*)d_in[18]; const float* bl3 = (const float*)d_in[19];
    float* out = (float*)d_out;

    const int NMAX = NB * N0;  // 65536

    char* p = (char*)d_ws;
    float* hW     = (float*)p; p += (size_t)NMAX * 128 * 4;
    float* hout   = (float*)p; p += (size_t)NMAX * 128 * 4;
    float* hA     = (float*)p; p += (size_t)NB * KP1 * 128 * 4;
    float* dis    = (float*)p; p += (size_t)NMAX * 4;
    float* hs     = (float*)p; p += (size_t)NMAX * 4;
    float* score  = (float*)p; p += (size_t)NMAX * 4;
    float* z      = (float*)p; p += (size_t)NB * 256 * 4;
    int* perm     = (int*)p;   p += (size_t)NB * KP1 * 4;
    int* newid    = (int*)p;   p += (size_t)NMAX * 4;
    int* srcb     = (int*)p;   p += (size_t)NEDGE * 4;
    int* dstb     = (int*)p;   p += (size_t)NEDGE * 4;
    int* emaskb   = (int*)p;   p += (size_t)NEDGE * 4;
    int* cnt      = (int*)p;   p += (size_t)NMAX * 4;
    int* off      = (int*)p;   p += (size_t)NMAX * 4;
    int* cursor   = (int*)p;   p += (size_t)NMAX * 4;
    int* gctr     = (int*)p;   p += 256;  // global region counter
    int* csr_src  = (int*)p;   p += (size_t)NEDGE * 4;

    const int EB = ceil_div(NEDGE, 256);

    init_edges_k<<<EB, 256, 0, stream>>>(ei, srcb, dstb, emaskb);
    hipMemsetAsync(z, 0, (size_t)NB * 256 * 4, stream);

    auto stage = [&](const float* Ain, int HI, int cur, int k,
                     const float* W, const float* bb,
                     const float* Wsc, const float* bsc) {
        int n = cur * NB;
        // CSR build (also yields deg -> dis)
        hipMemsetAsync(cnt, 0, (size_t)n * 4, stream);
        hipMemsetAsync(gctr, 0, 4, stream);
        if (HI == FIN)
            gemm_n128_k<FIN><<<ceil_div(n * 128, 256), 256, 0, stream>>>(Ain, W, hW, n);
        else
            gemm_n128_k<128><<<ceil_div(n * 128, 256), 256, 0, stream>>>(Ain, W, hW, n);
        count_k<<<EB, 256, 0, stream>>>(dstb, emaskb, cnt);
        offsets_k<<<ceil_div(n, 256), 256, 0, stream>>>(cnt, off, cursor, dis, gctr, n);
        scatter_k<<<EB, 256, 0, stream>>>(srcb, dstb, emaskb, cursor, csr_src);
        // fused GCN conv (+relu)
        gcn_agg_fused_k<<<ceil_div(n * 128, 256), 256, 0, stream>>>(hW, csr_src, off, cnt, dis, bb, hout, n);
        // score GCN (shares CSR/dis — same mask)
        gemv128_k<<<ceil_div(n, 256), 256, 0, stream>>>(hout, Wsc, hs, n);
        score_fused_k<<<ceil_div(n, 256), 256, 0, stream>>>(hs, csr_src, off, cnt, dis, bsc, score, n);
        // top-k pooling
        if (cur == N0)       topk_k<1024><<<NB, 256, 0, stream>>>(score, cur, k, perm);
        else if (cur == KP1) topk_k<256><<<NB, 256, 0, stream>>>(score, cur, k, perm);
        else                 topk_k<64><<<NB, 256, 0, stream>>>(score, cur, k, perm);
        hipMemsetAsync(newid, 0xFF, (size_t)n * 4, stream);
        scatter_newid_k<<<ceil_div(NB * k, 256), 256, 0, stream>>>(perm, newid, NB * k);
        pool_gather_k<<<ceil_div(NB * k * 128, 256), 256, 0, stream>>>(hout, score, perm, hA, NB * k);
        readout_add_k<<<NB, 128, 0, stream>>>(hA, z, k);
        edge_update_k<<<EB, 256, 0, stream>>>(srcb, dstb, emaskb, newid);
    };

    stage(x,  FIN, N0,  KP1, W1, b1, Ws1, bs1);
    stage(hA, 128, KP1, KP2, W2, b2, Ws2, bs2);
    stage(hA, 128, KP2, KP3, W3, b3, Ws3, bs3);

    mlp_head_k<<<NB, 128, 0, stream>>>(z, Wl1, bl1, Wl2, bl2, Wl3, bl3, out);
}

// Round 4
// 610.748 us; speedup vs baseline: 2.6158x; 1.2825x over previous
//
#include <hip/hip_runtime.h>
#include <math.h>

#define NB 64          // graphs
#define N0 1024        // nodes per graph (stage 1)
#define NEDGE 1048576  // total edges
#define FIN 10
#define HD 128
#define NCLS 10
#define KP1 205
#define KP2 41
#define KP3 9

static inline int ceil_div(int a, int b) { return (a + b - 1) / b; }

// ---------------- edge init / update (fused degree count) ----------------
__global__ void init_edges_count_k(const int* __restrict__ ei, int* __restrict__ srcb,
                                   int* __restrict__ dstb, int* __restrict__ em,
                                   int* __restrict__ cnt) {
    int e = blockIdx.x * blockDim.x + threadIdx.x;
    if (e >= NEDGE) return;
    int s = ei[e], d = ei[NEDGE + e];
    srcb[e] = s; dstb[e] = d; em[e] = 1;
    atomicAdd(&cnt[d], 1);
}

__global__ void edge_update_count_k(int* __restrict__ srcb, int* __restrict__ dstb,
                                    int* __restrict__ em, const int* __restrict__ newid,
                                    int* __restrict__ cnt) {
    int e = blockIdx.x * blockDim.x + threadIdx.x;
    if (e >= NEDGE) return;
    int m = em[e];
    int ns = 0, nd = 0;
    if (m) {
        ns = newid[srcb[e]];
        nd = newid[dstb[e]];
        if (ns < 0 || nd < 0) { m = 0; ns = 0; nd = 0; }
        else atomicAdd(&cnt[nd], 1);
    }
    srcb[e] = ns; dstb[e] = nd; em[e] = m;
}

// ---------------- CSR offsets: per-block scan + atomic block base ----------------
// Region ORDER across nodes is arbitrary — only disjointness matters for the gather.
__global__ void offsets_k(const int* __restrict__ cnt, int* __restrict__ off,
                          int* __restrict__ cursor, float* __restrict__ dis,
                          int* __restrict__ gctr, int n) {
    __shared__ int buf[256];
    __shared__ int base;
    int i = blockIdx.x * 256 + threadIdx.x;
    int v = (i < n) ? cnt[i] : 0;
    buf[threadIdx.x] = v;
    __syncthreads();
    #pragma unroll
    for (int s = 1; s < 256; s <<= 1) {
        int t = (threadIdx.x >= s) ? buf[threadIdx.x - s] : 0;
        __syncthreads();
        buf[threadIdx.x] += t;
        __syncthreads();
    }
    if (threadIdx.x == 255) base = atomicAdd(gctr, buf[255]);
    __syncthreads();
    if (i < n) {
        int excl = base + buf[threadIdx.x] - v;
        off[i] = excl;
        cursor[i] = excl;
        dis[i] = rsqrtf((float)v + 1.0f);
    }
}

__global__ void scatter_k(const int* __restrict__ srcb, const int* __restrict__ dstb,
                          const int* __restrict__ em, int* __restrict__ cursor,
                          int* __restrict__ csr_src) {
    int e = blockIdx.x * blockDim.x + threadIdx.x;
    if (e >= NEDGE) return;
    if (!em[e]) return;
    int p = atomicAdd(&cursor[dstb[e]], 1);
    csr_src[p] = srcb[e];
}

// ---------------- GEMM: C[n,128] = A[n,HI] @ W[HI,128] ----------------
template <int HI>
__global__ void gemm_n128_k(const float* __restrict__ A, const float* __restrict__ W,
                            float* __restrict__ C, int n) {
    __shared__ float Ws[64 * 128];
    int t = blockIdx.x * blockDim.x + threadIdx.x;
    int row = t >> 7, col = t & 127;
    float acc = 0.f;
    for (int k0 = 0; k0 < HI; k0 += 64) {
        int kc = (HI - k0) < 64 ? (HI - k0) : 64;
        __syncthreads();
        for (int i = threadIdx.x; i < kc * 128; i += blockDim.x) Ws[i] = W[k0 * 128 + i];
        __syncthreads();
        if (row < n) {
            const float* a = A + (size_t)row * HI + k0;
            #pragma unroll 8
            for (int i = 0; i < kc; ++i) acc += a[i] * Ws[i * 128 + col];
        }
    }
    if (row < n) C[(size_t)row * 128 + col] = acc;
}

// ---------- fused GCN aggregation: wave-per-node, float2, shfl-batched indices ----
// hout[i][f] = relu( dis[i]*sum_j hW[s_j][f]*dis[s_j] + hW[i][f]*dis[i]^2 + b[f] )
// Also fuses the score GEMV: hs[i] = hout[i][:] @ Wsc,  hsd[i] = hs[i]*dis[i].
__global__ void gcn_agg_fused2_k(const float* __restrict__ hW, const int* __restrict__ csr_src,
                                 const int* __restrict__ off, const int* __restrict__ cnt,
                                 const float* __restrict__ dis, const float* __restrict__ bias,
                                 const float* __restrict__ Wsc,
                                 float* __restrict__ hout, float* __restrict__ hs,
                                 float* __restrict__ hsd, int n) {
    int t = blockIdx.x * blockDim.x + threadIdx.x;
    int i = t >> 6;              // one wave per node
    int lane = threadIdx.x & 63; // feature pair id
    if (i >= n) return;
    const float2* hW2 = (const float2*)hW;
    int s0 = off[i], e0 = s0 + cnt[i];
    float accx = 0.f, accy = 0.f;
    for (int j0 = s0; j0 < e0; j0 += 64) {
        int rem = e0 - j0;
        int m = rem < 64 ? rem : 64;
        int sv = 0; float wv = 0.f;
        if (lane < m) { sv = csr_src[j0 + lane]; wv = dis[sv]; }
        int u = 0;
        for (; u + 4 <= m; u += 4) {
            int a0 = __shfl(sv, u + 0), a1 = __shfl(sv, u + 1);
            int a2 = __shfl(sv, u + 2), a3 = __shfl(sv, u + 3);
            float w0 = __shfl(wv, u + 0), w1 = __shfl(wv, u + 1);
            float w2 = __shfl(wv, u + 2), w3 = __shfl(wv, u + 3);
            float2 v0 = hW2[(size_t)a0 * 64 + lane];
            float2 v1 = hW2[(size_t)a1 * 64 + lane];
            float2 v2 = hW2[(size_t)a2 * 64 + lane];
            float2 v3 = hW2[(size_t)a3 * 64 + lane];
            accx += v0.x * w0 + v1.x * w1 + v2.x * w2 + v3.x * w3;
            accy += v0.y * w0 + v1.y * w1 + v2.y * w2 + v3.y * w3;
        }
        for (; u < m; ++u) {
            int s = __shfl(sv, u);
            float w = __shfl(wv, u);
            float2 v = hW2[(size_t)s * 64 + lane];
            accx += v.x * w; accy += v.y * w;
        }
    }
    float di = dis[i];
    float2 hv = hW2[(size_t)i * 64 + lane];
    float ox = fmaxf(di * accx + hv.x * (di * di) + bias[lane * 2], 0.f);
    float oy = fmaxf(di * accy + hv.y * (di * di) + bias[lane * 2 + 1], 0.f);
    float2 o; o.x = ox; o.y = oy;
    ((float2*)hout)[(size_t)i * 64 + lane] = o;
    // fused score GEMV: wave-reduce sum_f hout[i][f]*Wsc[f]
    float part = ox * Wsc[lane * 2] + oy * Wsc[lane * 2 + 1];
    #pragma unroll
    for (int sh = 32; sh >= 1; sh >>= 1) part += __shfl_xor(part, sh);
    if (lane == 0) { hs[i] = part; hsd[i] = part * di; }
}

// score[i] = dis[i] * sum_j hsd[src_j] + hs[i]*dis[i]^2 + bs
__global__ void score_fused_k(const float* __restrict__ hs, const float* __restrict__ hsd,
                              const int* __restrict__ csr_src,
                              const int* __restrict__ off, const int* __restrict__ cnt,
                              const float* __restrict__ dis, const float* __restrict__ bs,
                              float* __restrict__ score, int n) {
    int i = blockIdx.x * blockDim.x + threadIdx.x;
    if (i >= n) return;
    int s0 = off[i], e0 = s0 + cnt[i];
    float acc = 0.f;
    int j = s0;
    for (; j + 8 <= e0; j += 8) {
        int sx[8];
        #pragma unroll
        for (int u = 0; u < 8; ++u) sx[u] = csr_src[j + u];
        #pragma unroll
        for (int u = 0; u < 8; ++u) acc += hsd[sx[u]];
    }
    for (; j < e0; ++j) acc += hsd[csr_src[j]];
    float di = dis[i];
    score[i] = di * acc + hs[i] * (di * di) + bs[0];
}

// ---------------- per-graph top-k via bitonic sort in LDS ----------------
template <int CAP>
__global__ void topk_k(const float* __restrict__ score, int cur, int k, int* __restrict__ perm) {
    __shared__ float v[CAP];
    __shared__ int ix[CAP];
    int b = blockIdx.x;
    for (int i = threadIdx.x; i < CAP; i += blockDim.x) {
        v[i] = (i < cur) ? score[b * cur + i] : -INFINITY;
        ix[i] = i;
    }
    __syncthreads();
    for (int size = 2; size <= CAP; size <<= 1) {
        for (int stride = size >> 1; stride > 0; stride >>= 1) {
            for (int i = threadIdx.x; i < CAP / 2; i += blockDim.x) {
                int pos = 2 * i - (i & (stride - 1));
                int j = pos + stride;
                bool asc = (pos & size) == 0;
                float v0 = v[pos], v1 = v[j];
                int i0 = ix[pos], i1 = ix[j];
                bool jb = (v1 > v0) || (v1 == v0 && i1 < i0);  // j-before-pos in (desc, idx asc)
                bool sw = asc ? jb : !jb;
                if (sw) { v[pos] = v1; v[j] = v0; ix[pos] = i1; ix[j] = i0; }
            }
            __syncthreads();
        }
    }
    for (int j = threadIdx.x; j < k; j += blockDim.x)
        perm[b * k + j] = b * cur + ix[j];
}

__global__ void scatter_newid_k(const int* __restrict__ perm, int* __restrict__ newid, int nk) {
    int i = blockIdx.x * blockDim.x + threadIdx.x;
    if (i < nk) newid[perm[i]] = i;
}

__global__ void pool_gather_k(const float* __restrict__ hout, const float* __restrict__ score,
                              const int* __restrict__ perm, float* __restrict__ hA, int nk) {
    int t = blockIdx.x * blockDim.x + threadIdx.x;
    if (t >= nk * 128) return;
    int i = t >> 7, f = t & 127;
    int p = perm[i];
    hA[t] = hout[(size_t)p * 128 + f] * tanhf(score[p]);
}

// ---------------- readout: z[b] += concat(max_j, mean_j) ----------------
__global__ void readout_add_k(const float* __restrict__ x, float* __restrict__ z, int k) {
    int b = blockIdx.x, f = threadIdx.x;  // 128 threads
    const float* p = x + (size_t)b * k * 128 + f;
    float m = -INFINITY, s = 0.f;
    for (int j = 0; j < k; ++j) {
        float vv = p[(size_t)j * 128];
        m = fmaxf(m, vv);
        s += vv;
    }
    z[b * 256 + f] += m;
    z[b * 256 + 128 + f] += s / (float)k;
}

// ---------------- MLP head + log_softmax ----------------
__global__ void mlp_head_k(const float* __restrict__ z,
                           const float* __restrict__ Wl1, const float* __restrict__ bl1,
                           const float* __restrict__ Wl2, const float* __restrict__ bl2,
                           const float* __restrict__ Wl3, const float* __restrict__ bl3,
                           float* __restrict__ out) {
    __shared__ float zr[256], h1[128], h2[64], lg[NCLS], red[2];
    int b = blockIdx.x, t = threadIdx.x;  // 128 threads
    zr[t] = z[b * 256 + t];
    zr[t + 128] = z[b * 256 + 128 + t];
    __syncthreads();
    float acc = bl1[t];
    #pragma unroll 8
    for (int i = 0; i < 256; ++i) acc += zr[i] * Wl1[i * 128 + t];
    h1[t] = fmaxf(acc, 0.f);
    __syncthreads();
    if (t < 64) {
        float a2 = bl2[t];
        #pragma unroll 8
        for (int i = 0; i < 128; ++i) a2 += h1[i] * Wl2[i * 64 + t];
        h2[t] = fmaxf(a2, 0.f);
    }
    __syncthreads();
    if (t < NCLS) {
        float a3 = bl3[t];
        #pragma unroll 8
        for (int i = 0; i < 64; ++i) a3 += h2[i] * Wl3[i * NCLS + t];
        lg[t] = a3;
    }
    __syncthreads();
    if (t == 0) {
        float m = lg[0];
        for (int i = 1; i < NCLS; ++i) m = fmaxf(m, lg[i]);
        float s = 0.f;
        for (int i = 0; i < NCLS; ++i) s += expf(lg[i] - m);
        red[0] = m; red[1] = logf(s);
    }
    __syncthreads();
    if (t < NCLS) out[b * NCLS + t] = lg[t] - red[0] - red[1];
}

// ---------------- host ----------------
extern "C" void kernel_launch(void* const* d_in, const int* in_sizes, int n_in,
                              void* d_out, int out_size, void* d_ws, size_t ws_size,
                              hipStream_t stream) {
    const float* x   = (const float*)d_in[0];
    const int*   ei  = (const int*)d_in[1];
    const float* W1  = (const float*)d_in[2];  const float* b1  = (const float*)d_in[3];
    const float* W2  = (const float*)d_in[4];  const float* b2  = (const float*)d_in[5];
    const float* W3  = (const float*)d_in[6];  const float* b3  = (const float*)d_in[7];
    const float* Ws1 = (const float*)d_in[8];  const float* bs1 = (const float*)d_in[9];
    const float* Ws2 = (const float*)d_in[10]; const float* bs2 = (const float*)d_in[11];
    const float* Ws3 = (const float*)d_in[12]; const float* bs3 = (const float*)d_in[13];
    const float* Wl1 = (const float*)d_in[14]; const float* bl1 = (const float*)d_in[15];
    const float* Wl2 = (const float*)d_in[16]; const float* bl2 = (const float*)d_in[17];
    const float* Wl3 = (const float*)d_in[18]; const float* bl3 = (const float*)d_in[19];
    float* out = (float*)d_out;

    const int NMAX = NB * N0;  // 65536

    char* p = (char*)d_ws;
    float* hW     = (float*)p; p += (size_t)NMAX * 128 * 4;
    float* hout   = (float*)p; p += (size_t)NMAX * 128 * 4;
    float* hA     = (float*)p; p += (size_t)NB * KP1 * 128 * 4;
    float* dis    = (float*)p; p += (size_t)NMAX * 4;
    float* hs     = (float*)p; p += (size_t)NMAX * 4;
    float* hsd    = (float*)p; p += (size_t)NMAX * 4;
    float* score  = (float*)p; p += (size_t)NMAX * 4;
    float* z      = (float*)p; p += (size_t)NB * 256 * 4;
    int* perm     = (int*)p;   p += (size_t)NB * KP1 * 4;
    int* newid    = (int*)p;   p += (size_t)NMAX * 4;
    int* srcb     = (int*)p;   p += (size_t)NEDGE * 4;
    int* dstb     = (int*)p;   p += (size_t)NEDGE * 4;
    int* emaskb   = (int*)p;   p += (size_t)NEDGE * 4;
    int* cnt      = (int*)p;   p += (size_t)NMAX * 4;
    int* off      = (int*)p;   p += (size_t)NMAX * 4;
    int* cursor   = (int*)p;   p += (size_t)NMAX * 4;
    int* gctr     = (int*)p;   p += 256;  // global region counter
    int* csr_src  = (int*)p;   p += (size_t)NEDGE * 4;

    const int EB = ceil_div(NEDGE, 256);

    hipMemsetAsync(cnt, 0, (size_t)NMAX * 4, stream);
    init_edges_count_k<<<EB, 256, 0, stream>>>(ei, srcb, dstb, emaskb, cnt);
    hipMemsetAsync(z, 0, (size_t)NB * 256 * 4, stream);

    auto stage = [&](const float* Ain, int HI, int cur, int k,
                     const float* W, const float* bb,
                     const float* Wsc, const float* bsc, bool last) {
        int n = cur * NB;
        hipMemsetAsync(gctr, 0, 4, stream);
        if (HI == FIN)
            gemm_n128_k<FIN><<<ceil_div(n * 128, 256), 256, 0, stream>>>(Ain, W, hW, n);
        else
            gemm_n128_k<128><<<ceil_div(n * 128, 256), 256, 0, stream>>>(Ain, W, hW, n);
        offsets_k<<<ceil_div(n, 256), 256, 0, stream>>>(cnt, off, cursor, dis, gctr, n);
        scatter_k<<<EB, 256, 0, stream>>>(srcb, dstb, emaskb, cursor, csr_src);
        // fused GCN conv (+relu) + score GEMV
        gcn_agg_fused2_k<<<ceil_div(n * 64, 256), 256, 0, stream>>>(
            hW, csr_src, off, cnt, dis, bb, Wsc, hout, hs, hsd, n);
        score_fused_k<<<ceil_div(n, 256), 256, 0, stream>>>(hs, hsd, csr_src, off, cnt, dis, bsc, score, n);
        // top-k pooling
        if (cur == N0)       topk_k<1024><<<NB, 512, 0, stream>>>(score, cur, k, perm);
        else if (cur == KP1) topk_k<256><<<NB, 128, 0, stream>>>(score, cur, k, perm);
        else                 topk_k<64><<<NB, 64, 0, stream>>>(score, cur, k, perm);
        pool_gather_k<<<ceil_div(NB * k * 128, 256), 256, 0, stream>>>(hout, score, perm, hA, NB * k);
        readout_add_k<<<NB, 128, 0, stream>>>(hA, z, k);
        if (!last) {
            hipMemsetAsync(newid, 0xFF, (size_t)n * 4, stream);
            scatter_newid_k<<<ceil_div(NB * k, 256), 256, 0, stream>>>(perm, newid, NB * k);
            hipMemsetAsync(cnt, 0, (size_t)NB * k * 4, stream);
            edge_update_count_k<<<EB, 256, 0, stream>>>(srcb, dstb, emaskb, newid, cnt);
        }
    };

    stage(x,  FIN, N0,  KP1, W1, b1, Ws1, bs1, false);
    stage(hA, 128, KP1, KP2, W2, b2, Ws2, bs2, false);
    stage(hA, 128, KP2, KP3, W3, b3, Ws3, bs3, true);

    mlp_head_k<<<NB, 128, 0, stream>>>(z, Wl1, bl1, Wl2, bl2, Wl3, bl3, out);
}

// Round 5
// 473.520 us; speedup vs baseline: 3.3739x; 1.2898x over previous
//
#include <hip/hip_runtime.h>
#include <math.h>

#define NB 64          // graphs
#define N0 1024        // nodes per graph (stage 1)
#define NEDGE 1048576  // total edges
#define FIN 10
#define HD 128
#define NCLS 10
#define KP1 205
#define KP2 41
#define KP3 9

static inline int ceil_div(int a, int b) { return (a + b - 1) / b; }

// ---------------- edge init / update (fused degree count) ----------------
__global__ void init_edges_count_k(const int* __restrict__ ei, int* __restrict__ srcb,
                                   int* __restrict__ dstb, int* __restrict__ em,
                                   int* __restrict__ cnt) {
    int e = blockIdx.x * blockDim.x + threadIdx.x;
    if (e >= NEDGE) return;
    int s = ei[e], d = ei[NEDGE + e];
    srcb[e] = s; dstb[e] = d; em[e] = 1;
    atomicAdd(&cnt[d], 1);
}

__global__ void edge_update_count_k(int* __restrict__ srcb, int* __restrict__ dstb,
                                    int* __restrict__ em, const int* __restrict__ newid,
                                    int* __restrict__ cnt) {
    int e = blockIdx.x * blockDim.x + threadIdx.x;
    if (e >= NEDGE) return;
    int m = em[e];
    int ns = 0, nd = 0;
    if (m) {
        ns = newid[srcb[e]];
        nd = newid[dstb[e]];
        if (ns < 0 || nd < 0) { m = 0; ns = 0; nd = 0; }
        else atomicAdd(&cnt[nd], 1);
    }
    srcb[e] = ns; dstb[e] = nd; em[e] = m;
}

// ---------------- CSR offsets: per-block scan + atomic block base ----------------
__global__ void offsets_k(const int* __restrict__ cnt, int* __restrict__ off,
                          int* __restrict__ cursor, float* __restrict__ dis,
                          int* __restrict__ gctr, int n) {
    __shared__ int buf[256];
    __shared__ int base;
    int i = blockIdx.x * 256 + threadIdx.x;
    int v = (i < n) ? cnt[i] : 0;
    buf[threadIdx.x] = v;
    __syncthreads();
    #pragma unroll
    for (int s = 1; s < 256; s <<= 1) {
        int t = (threadIdx.x >= s) ? buf[threadIdx.x - s] : 0;
        __syncthreads();
        buf[threadIdx.x] += t;
        __syncthreads();
    }
    if (threadIdx.x == 255) base = atomicAdd(gctr, buf[255]);
    __syncthreads();
    if (i < n) {
        int excl = base + buf[threadIdx.x] - v;
        off[i] = excl;
        cursor[i] = excl;
        dis[i] = rsqrtf((float)v + 1.0f);
    }
}

__global__ void scatter_k(const int* __restrict__ srcb, const int* __restrict__ dstb,
                          const int* __restrict__ em, int* __restrict__ cursor,
                          int* __restrict__ csr_src) {
    int e = blockIdx.x * blockDim.x + threadIdx.x;
    if (e >= NEDGE) return;
    if (!em[e]) return;
    int p = atomicAdd(&cursor[dstb[e]], 1);
    csr_src[p] = srcb[e];
}

// ---------------- GEMM (K=10): wave per row, W in LDS, shfl-broadcast A --------
__global__ void gemm_fin_k(const float* __restrict__ A, const float* __restrict__ W,
                           float* __restrict__ C, int n) {
    __shared__ float Ws[FIN * 128];
    for (int i = threadIdx.x; i < FIN * 128; i += blockDim.x) Ws[i] = W[i];
    __syncthreads();
    int t = blockIdx.x * blockDim.x + threadIdx.x;
    int i = t >> 6, lane = threadIdx.x & 63;
    if (i >= n) return;
    float a = (lane < FIN) ? A[(size_t)i * FIN + lane] : 0.f;
    const float2* W2 = (const float2*)Ws;
    float ax = 0.f, ay = 0.f;
    #pragma unroll
    for (int k = 0; k < FIN; ++k) {
        float ak = __shfl(a, k);
        float2 w = W2[k * 64 + lane];
        ax += ak * w.x; ay += ak * w.y;
    }
    float2 o; o.x = ax; o.y = ay;
    ((float2*)C)[(size_t)i * 64 + lane] = o;
}

// ---------------- GEMM (K=128): 64x64 tile, 4x4 per thread, register-tiled -----
__global__ __launch_bounds__(256) void gemm128_tiled_k(const float* __restrict__ A,
                                                       const float* __restrict__ W,
                                                       float* __restrict__ C, int n) {
    __shared__ float As[64][33];   // +1 pad
    __shared__ float Wt[32][64];
    int tx = threadIdx.x & 15, ty = threadIdx.x >> 4;
    int r0 = blockIdx.x * 64;
    int c0 = blockIdx.y * 64;
    float4 acc0 = {0,0,0,0}, acc1 = {0,0,0,0}, acc2 = {0,0,0,0}, acc3 = {0,0,0,0};
    int u = threadIdx.x;
    for (int k0 = 0; k0 < 128; k0 += 32) {
        __syncthreads();
        {   // stage A: 64 rows x 32 k, float4 along K
            int rr = u >> 3, cc = (u & 7) * 4;
            #pragma unroll
            for (int h = 0; h < 2; ++h) {
                int r = rr + h * 32;
                float4 v = {0,0,0,0};
                if (r0 + r < n) v = *(const float4*)&A[(size_t)(r0 + r) * 128 + k0 + cc];
                As[r][cc] = v.x; As[r][cc+1] = v.y; As[r][cc+2] = v.z; As[r][cc+3] = v.w;
            }
        }
        {   // stage W: 32 k x 64 cols, float4 along cols
            int kk = u >> 4, c = (u & 15) * 4;
            #pragma unroll
            for (int h = 0; h < 2; ++h) {
                float4 v = *(const float4*)&W[(size_t)(k0 + kk + h * 16) * 128 + c0 + c];
                *(float4*)&Wt[kk + h * 16][c] = v;
            }
        }
        __syncthreads();
        #pragma unroll
        for (int kk = 0; kk < 32; ++kk) {
            float4 wv = *(const float4*)&Wt[kk][tx * 4];
            float a0 = As[ty * 4 + 0][kk];
            float a1 = As[ty * 4 + 1][kk];
            float a2 = As[ty * 4 + 2][kk];
            float a3 = As[ty * 4 + 3][kk];
            acc0.x += a0 * wv.x; acc0.y += a0 * wv.y; acc0.z += a0 * wv.z; acc0.w += a0 * wv.w;
            acc1.x += a1 * wv.x; acc1.y += a1 * wv.y; acc1.z += a1 * wv.z; acc1.w += a1 * wv.w;
            acc2.x += a2 * wv.x; acc2.y += a2 * wv.y; acc2.z += a2 * wv.z; acc2.w += a2 * wv.w;
            acc3.x += a3 * wv.x; acc3.y += a3 * wv.y; acc3.z += a3 * wv.z; acc3.w += a3 * wv.w;
        }
    }
    int r = r0 + ty * 4;
    if (r + 0 < n) *(float4*)&C[(size_t)(r + 0) * 128 + c0 + tx * 4] = acc0;
    if (r + 1 < n) *(float4*)&C[(size_t)(r + 1) * 128 + c0 + tx * 4] = acc1;
    if (r + 2 < n) *(float4*)&C[(size_t)(r + 2) * 128 + c0 + tx * 4] = acc2;
    if (r + 3 < n) *(float4*)&C[(size_t)(r + 3) * 128 + c0 + tx * 4] = acc3;
}

// ---------- fused GCN aggregation: wave-per-node, float2, shfl-batched indices ----
__global__ void gcn_agg_fused2_k(const float* __restrict__ hW, const int* __restrict__ csr_src,
                                 const int* __restrict__ off, const int* __restrict__ cnt,
                                 const float* __restrict__ dis, const float* __restrict__ bias,
                                 const float* __restrict__ Wsc,
                                 float* __restrict__ hout, float* __restrict__ hs,
                                 float* __restrict__ hsd, int n) {
    int t = blockIdx.x * blockDim.x + threadIdx.x;
    int i = t >> 6;              // one wave per node
    int lane = threadIdx.x & 63; // feature pair id
    if (i >= n) return;
    const float2* hW2 = (const float2*)hW;
    int s0 = off[i], e0 = s0 + cnt[i];
    float accx = 0.f, accy = 0.f;
    for (int j0 = s0; j0 < e0; j0 += 64) {
        int rem = e0 - j0;
        int m = rem < 64 ? rem : 64;
        int sv = 0; float wv = 0.f;
        if (lane < m) { sv = csr_src[j0 + lane]; wv = dis[sv]; }
        int u = 0;
        for (; u + 4 <= m; u += 4) {
            int a0 = __shfl(sv, u + 0), a1 = __shfl(sv, u + 1);
            int a2 = __shfl(sv, u + 2), a3 = __shfl(sv, u + 3);
            float w0 = __shfl(wv, u + 0), w1 = __shfl(wv, u + 1);
            float w2 = __shfl(wv, u + 2), w3 = __shfl(wv, u + 3);
            float2 v0 = hW2[(size_t)a0 * 64 + lane];
            float2 v1 = hW2[(size_t)a1 * 64 + lane];
            float2 v2 = hW2[(size_t)a2 * 64 + lane];
            float2 v3 = hW2[(size_t)a3 * 64 + lane];
            accx += v0.x * w0 + v1.x * w1 + v2.x * w2 + v3.x * w3;
            accy += v0.y * w0 + v1.y * w1 + v2.y * w2 + v3.y * w3;
        }
        for (; u < m; ++u) {
            int s = __shfl(sv, u);
            float w = __shfl(wv, u);
            float2 v = hW2[(size_t)s * 64 + lane];
            accx += v.x * w; accy += v.y * w;
        }
    }
    float di = dis[i];
    float2 hv = hW2[(size_t)i * 64 + lane];
    float ox = fmaxf(di * accx + hv.x * (di * di) + bias[lane * 2], 0.f);
    float oy = fmaxf(di * accy + hv.y * (di * di) + bias[lane * 2 + 1], 0.f);
    float2 o; o.x = ox; o.y = oy;
    ((float2*)hout)[(size_t)i * 64 + lane] = o;
    float part = ox * Wsc[lane * 2] + oy * Wsc[lane * 2 + 1];
    #pragma unroll
    for (int sh = 32; sh >= 1; sh >>= 1) part += __shfl_xor(part, sh);
    if (lane == 0) { hs[i] = part; hsd[i] = part * di; }
}

// score[i] = dis[i] * sum_j hsd[src_j] + hs[i]*dis[i]^2 + bs
__global__ void score_fused_k(const float* __restrict__ hs, const float* __restrict__ hsd,
                              const int* __restrict__ csr_src,
                              const int* __restrict__ off, const int* __restrict__ cnt,
                              const float* __restrict__ dis, const float* __restrict__ bs,
                              float* __restrict__ score, int n) {
    int i = blockIdx.x * blockDim.x + threadIdx.x;
    if (i >= n) return;
    int s0 = off[i], e0 = s0 + cnt[i];
    float acc = 0.f;
    int j = s0;
    for (; j + 8 <= e0; j += 8) {
        int sx[8];
        #pragma unroll
        for (int u = 0; u < 8; ++u) sx[u] = csr_src[j + u];
        #pragma unroll
        for (int u = 0; u < 8; ++u) acc += hsd[sx[u]];
    }
    for (; j < e0; ++j) acc += hsd[csr_src[j]];
    float di = dis[i];
    score[i] = di * acc + hs[i] * (di * di) + bs[0];
}

// ---------------- per-graph top-k via bitonic sort in LDS ----------------
template <int CAP>
__global__ void topk_k(const float* __restrict__ score, int cur, int k, int* __restrict__ perm) {
    __shared__ float v[CAP];
    __shared__ int ix[CAP];
    int b = blockIdx.x;
    for (int i = threadIdx.x; i < CAP; i += blockDim.x) {
        v[i] = (i < cur) ? score[b * cur + i] : -INFINITY;
        ix[i] = i;
    }
    __syncthreads();
    for (int size = 2; size <= CAP; size <<= 1) {
        for (int stride = size >> 1; stride > 0; stride >>= 1) {
            for (int i = threadIdx.x; i < CAP / 2; i += blockDim.x) {
                int pos = 2 * i - (i & (stride - 1));
                int j = pos + stride;
                bool asc = (pos & size) == 0;
                float v0 = v[pos], v1 = v[j];
                int i0 = ix[pos], i1 = ix[j];
                bool jb = (v1 > v0) || (v1 == v0 && i1 < i0);
                bool sw = asc ? jb : !jb;
                if (sw) { v[pos] = v1; v[j] = v0; ix[pos] = i1; ix[j] = i0; }
            }
            __syncthreads();
        }
    }
    for (int j = threadIdx.x; j < k; j += blockDim.x)
        perm[b * k + j] = b * cur + ix[j];
}

__global__ void scatter_newid_k(const int* __restrict__ perm, int* __restrict__ newid, int nk) {
    int i = blockIdx.x * blockDim.x + threadIdx.x;
    if (i < nk) newid[perm[i]] = i;
}

__global__ void pool_gather_k(const float* __restrict__ hout, const float* __restrict__ score,
                              const int* __restrict__ perm, float* __restrict__ hA, int nk) {
    int t = blockIdx.x * blockDim.x + threadIdx.x;
    if (t >= nk * 128) return;
    int i = t >> 7, f = t & 127;
    int p = perm[i];
    hA[t] = hout[(size_t)p * 128 + f] * tanhf(score[p]);
}

// ---------------- readout: z[b] += concat(max_j, mean_j) ----------------
__global__ void readout_add_k(const float* __restrict__ x, float* __restrict__ z, int k) {
    int b = blockIdx.x, f = threadIdx.x;  // 128 threads
    const float* p = x + (size_t)b * k * 128 + f;
    float m = -INFINITY, s = 0.f;
    for (int j = 0; j < k; ++j) {
        float vv = p[(size_t)j * 128];
        m = fmaxf(m, vv);
        s += vv;
    }
    z[b * 256 + f] += m;
    z[b * 256 + 128 + f] += s / (float)k;
}

// ---------------- MLP head + log_softmax ----------------
__global__ void mlp_head_k(const float* __restrict__ z,
                           const float* __restrict__ Wl1, const float* __restrict__ bl1,
                           const float* __restrict__ Wl2, const float* __restrict__ bl2,
                           const float* __restrict__ Wl3, const float* __restrict__ bl3,
                           float* __restrict__ out) {
    __shared__ float zr[256], h1[128], h2[64], lg[NCLS], red[2];
    int b = blockIdx.x, t = threadIdx.x;  // 128 threads
    zr[t] = z[b * 256 + t];
    zr[t + 128] = z[b * 256 + 128 + t];
    __syncthreads();
    float acc = bl1[t];
    #pragma unroll 8
    for (int i = 0; i < 256; ++i) acc += zr[i] * Wl1[i * 128 + t];
    h1[t] = fmaxf(acc, 0.f);
    __syncthreads();
    if (t < 64) {
        float a2 = bl2[t];
        #pragma unroll 8
        for (int i = 0; i < 128; ++i) a2 += h1[i] * Wl2[i * 64 + t];
        h2[t] = fmaxf(a2, 0.f);
    }
    __syncthreads();
    if (t < NCLS) {
        float a3 = bl3[t];
        #pragma unroll 8
        for (int i = 0; i < 64; ++i) a3 += h2[i] * Wl3[i * NCLS + t];
        lg[t] = a3;
    }
    __syncthreads();
    if (t == 0) {
        float m = lg[0];
        for (int i = 1; i < NCLS; ++i) m = fmaxf(m, lg[i]);
        float s = 0.f;
        for (int i = 0; i < NCLS; ++i) s += expf(lg[i] - m);
        red[0] = m; red[1] = logf(s);
    }
    __syncthreads();
    if (t < NCLS) out[b * NCLS + t] = lg[t] - red[0] - red[1];
}

// ---------------- host ----------------
extern "C" void kernel_launch(void* const* d_in, const int* in_sizes, int n_in,
                              void* d_out, int out_size, void* d_ws, size_t ws_size,
                              hipStream_t stream) {
    const float* x   = (const float*)d_in[0];
    const int*   ei  = (const int*)d_in[1];
    const float* W1  = (const float*)d_in[2];  const float* b1  = (const float*)d_in[3];
    const float* W2  = (const float*)d_in[4];  const float* b2  = (const float*)d_in[5];
    const float* W3  = (const float*)d_in[6];  const float* b3  = (const float*)d_in[7];
    const float* Ws1 = (const float*)d_in[8];  const float* bs1 = (const float*)d_in[9];
    const float* Ws2 = (const float*)d_in[10]; const float* bs2 = (const float*)d_in[11];
    const float* Ws3 = (const float*)d_in[12]; const float* bs3 = (const float*)d_in[13];
    const float* Wl1 = (const float*)d_in[14]; const float* bl1 = (const float*)d_in[15];
    const float* Wl2 = (const float*)d_in[16]; const float* bl2 = (const float*)d_in[17];
    const float* Wl3 = (const float*)d_in[18]; const float* bl3 = (const float*)d_in[19];
    float* out = (float*)d_out;

    const int NMAX = NB * N0;  // 65536

    char* p = (char*)d_ws;
    float* hW     = (float*)p; p += (size_t)NMAX * 128 * 4;
    float* hout   = (float*)p; p += (size_t)NMAX * 128 * 4;
    float* hA     = (float*)p; p += (size_t)NB * KP1 * 128 * 4;
    float* dis    = (float*)p; p += (size_t)NMAX * 4;
    float* hs     = (float*)p; p += (size_t)NMAX * 4;
    float* hsd    = (float*)p; p += (size_t)NMAX * 4;
    float* score  = (float*)p; p += (size_t)NMAX * 4;
    float* z      = (float*)p; p += (size_t)NB * 256 * 4;
    int* perm     = (int*)p;   p += (size_t)NB * KP1 * 4;
    int* newid    = (int*)p;   p += (size_t)NMAX * 4;
    int* srcb     = (int*)p;   p += (size_t)NEDGE * 4;
    int* dstb     = (int*)p;   p += (size_t)NEDGE * 4;
    int* emaskb   = (int*)p;   p += (size_t)NEDGE * 4;
    int* cnt      = (int*)p;   p += (size_t)NMAX * 4;
    int* off      = (int*)p;   p += (size_t)NMAX * 4;
    int* cursor   = (int*)p;   p += (size_t)NMAX * 4;
    int* gctr     = (int*)p;   p += 256;  // global region counter
    int* csr_src  = (int*)p;   p += (size_t)NEDGE * 4;

    const int EB = ceil_div(NEDGE, 256);

    hipMemsetAsync(cnt, 0, (size_t)NMAX * 4, stream);
    init_edges_count_k<<<EB, 256, 0, stream>>>(ei, srcb, dstb, emaskb, cnt);
    hipMemsetAsync(z, 0, (size_t)NB * 256 * 4, stream);

    auto stage = [&](const float* Ain, int HI, int cur, int k,
                     const float* W, const float* bb,
                     const float* Wsc, const float* bsc, bool last) {
        int n = cur * NB;
        hipMemsetAsync(gctr, 0, 4, stream);
        if (HI == FIN) {
            gemm_fin_k<<<ceil_div(n * 64, 256), 256, 0, stream>>>(Ain, W, hW, n);
        } else {
            dim3 g(ceil_div(n, 64), 2);
            gemm128_tiled_k<<<g, 256, 0, stream>>>(Ain, W, hW, n);
        }
        offsets_k<<<ceil_div(n, 256), 256, 0, stream>>>(cnt, off, cursor, dis, gctr, n);
        scatter_k<<<EB, 256, 0, stream>>>(srcb, dstb, emaskb, cursor, csr_src);
        gcn_agg_fused2_k<<<ceil_div(n * 64, 256), 256, 0, stream>>>(
            hW, csr_src, off, cnt, dis, bb, Wsc, hout, hs, hsd, n);
        score_fused_k<<<ceil_div(n, 256), 256, 0, stream>>>(hs, hsd, csr_src, off, cnt, dis, bsc, score, n);
        if (cur == N0)       topk_k<1024><<<NB, 512, 0, stream>>>(score, cur, k, perm);
        else if (cur == KP1) topk_k<256><<<NB, 128, 0, stream>>>(score, cur, k, perm);
        else                 topk_k<64><<<NB, 64, 0, stream>>>(score, cur, k, perm);
        pool_gather_k<<<ceil_div(NB * k * 128, 256), 256, 0, stream>>>(hout, score, perm, hA, NB * k);
        readout_add_k<<<NB, 128, 0, stream>>>(hA, z, k);
        if (!last) {
            hipMemsetAsync(newid, 0xFF, (size_t)n * 4, stream);
            scatter_newid_k<<<ceil_div(NB * k, 256), 256, 0, stream>>>(perm, newid, NB * k);
            hipMemsetAsync(cnt, 0, (size_t)NB * k * 4, stream);
            edge_update_count_k<<<EB, 256, 0, stream>>>(srcb, dstb, emaskb, newid, cnt);
        }
    };

    stage(x,  FIN, N0,  KP1, W1, b1, Ws1, bs1, false);
    stage(hA, 128, KP1, KP2, W2, b2, Ws2, bs2, false);
    stage(hA, 128, KP2, KP3, W3, b3, Ws3, bs3, true);

    mlp_head_k<<<NB, 128, 0, stream>>>(z, Wl1, bl1, Wl2, bl2, Wl3, bl3, out);
}

// Round 6
// 373.548 us; speedup vs baseline: 4.2769x; 1.2676x over previous
//
#include <hip/hip_runtime.h>
#include <math.h>

#define NB 64          // graphs
#define N0 1024        // nodes per graph (stage 1)
#define NEDGE 1048576  // total edges
#define FIN 10
#define HD 128
#define NCLS 10
#define KP1 205
#define KP2 41
#define KP3 9

static inline int ceil_div(int a, int b) { return (a + b - 1) / b; }

// ---------------- edge init (int2, fused degree count) ----------------
__global__ void init_edges_count_k(const int* __restrict__ ei, int2* __restrict__ eb,
                                   int* __restrict__ cnt) {
    int e = blockIdx.x * blockDim.x + threadIdx.x;
    if (e >= NEDGE) return;
    int2 ed; ed.x = ei[e]; ed.y = ei[NEDGE + e];
    eb[e] = ed;
    atomicAdd(&cnt[ed.y], 1);
}

// remap edges through newid; masked edges get y=-1; count new degrees
__global__ void edge_update_count_k(int2* __restrict__ eb, const int* __restrict__ newid,
                                    int* __restrict__ cntN) {
    int e = blockIdx.x * blockDim.x + threadIdx.x;
    if (e >= NEDGE) return;
    int2 ed = eb[e];
    if (ed.y < 0) return;  // already dead, no write
    int ns = newid[ed.x], nd = newid[ed.y];
    if (ns < 0 || nd < 0) { ed.x = 0; ed.y = -1; }
    else { ed.x = ns; ed.y = nd; atomicAdd(&cntN[nd], 1); }
    eb[e] = ed;
}

// ---------------- CSR offsets: per-block scan + atomic block base ----------------
// Region ORDER across nodes is arbitrary — only disjointness matters for the gather.
__global__ void offsets_k(const int* __restrict__ cnt, int* __restrict__ off,
                          int* __restrict__ cursor, float* __restrict__ dis,
                          int* __restrict__ gctr, int n) {
    __shared__ int buf[256];
    __shared__ int base;
    int i = blockIdx.x * 256 + threadIdx.x;
    int v = (i < n) ? cnt[i] : 0;
    buf[threadIdx.x] = v;
    __syncthreads();
    #pragma unroll
    for (int s = 1; s < 256; s <<= 1) {
        int t = (threadIdx.x >= s) ? buf[threadIdx.x - s] : 0;
        __syncthreads();
        buf[threadIdx.x] += t;
        __syncthreads();
    }
    if (threadIdx.x == 255) base = atomicAdd(gctr, buf[255]);
    __syncthreads();
    if (i < n) {
        int excl = base + buf[threadIdx.x] - v;
        off[i] = excl;
        cursor[i] = excl;
        dis[i] = rsqrtf((float)v + 1.0f);
    }
}

__global__ void scatter_k(const int2* __restrict__ eb, int* __restrict__ cursor,
                          int* __restrict__ csr_src) {
    int e = blockIdx.x * blockDim.x + threadIdx.x;
    if (e >= NEDGE) return;
    int2 ed = eb[e];
    if (ed.y < 0) return;
    int p = atomicAdd(&cursor[ed.y], 1);
    csr_src[p] = ed.x;
}

// ---------------- GEMM (K=10): wave per row, W in LDS, shfl-broadcast A --------
__global__ void gemm_fin_k(const float* __restrict__ A, const float* __restrict__ W,
                           float* __restrict__ C, int n) {
    __shared__ float Ws[FIN * 128];
    for (int i = threadIdx.x; i < FIN * 128; i += blockDim.x) Ws[i] = W[i];
    __syncthreads();
    int t = blockIdx.x * blockDim.x + threadIdx.x;
    int i = t >> 6, lane = threadIdx.x & 63;
    if (i >= n) return;
    float a = (lane < FIN) ? A[(size_t)i * FIN + lane] : 0.f;
    const float2* W2 = (const float2*)Ws;
    float ax = 0.f, ay = 0.f;
    #pragma unroll
    for (int k = 0; k < FIN; ++k) {
        float ak = __shfl(a, k);
        float2 w = W2[k * 64 + lane];
        ax += ak * w.x; ay += ak * w.y;
    }
    float2 o; o.x = ax; o.y = ay;
    ((float2*)C)[(size_t)i * 64 + lane] = o;
}

// ---------------- GEMM (K=128): 64x64 tile, 4x4 per thread, register-tiled -----
__global__ __launch_bounds__(256) void gemm128_tiled_k(const float* __restrict__ A,
                                                       const float* __restrict__ W,
                                                       float* __restrict__ C, int n) {
    __shared__ float As[64][33];
    __shared__ float Wt[32][64];
    int tx = threadIdx.x & 15, ty = threadIdx.x >> 4;
    int r0 = blockIdx.x * 64;
    int c0 = blockIdx.y * 64;
    float4 acc0 = {0,0,0,0}, acc1 = {0,0,0,0}, acc2 = {0,0,0,0}, acc3 = {0,0,0,0};
    int u = threadIdx.x;
    for (int k0 = 0; k0 < 128; k0 += 32) {
        __syncthreads();
        {
            int rr = u >> 3, cc = (u & 7) * 4;
            #pragma unroll
            for (int h = 0; h < 2; ++h) {
                int r = rr + h * 32;
                float4 v = {0,0,0,0};
                if (r0 + r < n) v = *(const float4*)&A[(size_t)(r0 + r) * 128 + k0 + cc];
                As[r][cc] = v.x; As[r][cc+1] = v.y; As[r][cc+2] = v.z; As[r][cc+3] = v.w;
            }
        }
        {
            int kk = u >> 4, c = (u & 15) * 4;
            #pragma unroll
            for (int h = 0; h < 2; ++h) {
                float4 v = *(const float4*)&W[(size_t)(k0 + kk + h * 16) * 128 + c0 + c];
                *(float4*)&Wt[kk + h * 16][c] = v;
            }
        }
        __syncthreads();
        #pragma unroll
        for (int kk = 0; kk < 32; ++kk) {
            float4 wv = *(const float4*)&Wt[kk][tx * 4];
            float a0 = As[ty * 4 + 0][kk];
            float a1 = As[ty * 4 + 1][kk];
            float a2 = As[ty * 4 + 2][kk];
            float a3 = As[ty * 4 + 3][kk];
            acc0.x += a0 * wv.x; acc0.y += a0 * wv.y; acc0.z += a0 * wv.z; acc0.w += a0 * wv.w;
            acc1.x += a1 * wv.x; acc1.y += a1 * wv.y; acc1.z += a1 * wv.z; acc1.w += a1 * wv.w;
            acc2.x += a2 * wv.x; acc2.y += a2 * wv.y; acc2.z += a2 * wv.z; acc2.w += a2 * wv.w;
            acc3.x += a3 * wv.x; acc3.y += a3 * wv.y; acc3.z += a3 * wv.z; acc3.w += a3 * wv.w;
        }
    }
    int r = r0 + ty * 4;
    if (r + 0 < n) *(float4*)&C[(size_t)(r + 0) * 128 + c0 + tx * 4] = acc0;
    if (r + 1 < n) *(float4*)&C[(size_t)(r + 1) * 128 + c0 + tx * 4] = acc1;
    if (r + 2 < n) *(float4*)&C[(size_t)(r + 2) * 128 + c0 + tx * 4] = acc2;
    if (r + 3 < n) *(float4*)&C[(size_t)(r + 3) * 128 + c0 + tx * 4] = acc3;
}

// ---------- fused GCN aggregation: wave-per-node, float2, shfl-batched indices ----
// XCD-swizzled: wg = (bid&7)*cpx + bid>>3 so each XCD works on contiguous graphs
// (its gather window then fits its private 4MB L2).
__global__ void gcn_agg_fused2_k(const float* __restrict__ hW, const int* __restrict__ csr_src,
                                 const int* __restrict__ off, const int* __restrict__ cnt,
                                 const float* __restrict__ dis, const float* __restrict__ bias,
                                 const float* __restrict__ Wsc,
                                 float* __restrict__ hout, float* __restrict__ hs,
                                 float* __restrict__ hsd, int n, int cpx) {
    int wg = ((blockIdx.x & 7) * cpx) + (blockIdx.x >> 3);
    int t = wg * blockDim.x + threadIdx.x;
    int i = t >> 6;              // one wave per node
    int lane = threadIdx.x & 63; // feature pair id
    if (i >= n) return;
    const float2* hW2 = (const float2*)hW;
    int s0 = off[i], e0 = s0 + cnt[i];
    float accx = 0.f, accy = 0.f;
    for (int j0 = s0; j0 < e0; j0 += 64) {
        int rem = e0 - j0;
        int m = rem < 64 ? rem : 64;
        int sv = 0; float wv = 0.f;
        if (lane < m) { sv = csr_src[j0 + lane]; wv = dis[sv]; }
        int u = 0;
        for (; u + 4 <= m; u += 4) {
            int a0 = __shfl(sv, u + 0), a1 = __shfl(sv, u + 1);
            int a2 = __shfl(sv, u + 2), a3 = __shfl(sv, u + 3);
            float w0 = __shfl(wv, u + 0), w1 = __shfl(wv, u + 1);
            float w2 = __shfl(wv, u + 2), w3 = __shfl(wv, u + 3);
            float2 v0 = hW2[(size_t)a0 * 64 + lane];
            float2 v1 = hW2[(size_t)a1 * 64 + lane];
            float2 v2 = hW2[(size_t)a2 * 64 + lane];
            float2 v3 = hW2[(size_t)a3 * 64 + lane];
            accx += v0.x * w0 + v1.x * w1 + v2.x * w2 + v3.x * w3;
            accy += v0.y * w0 + v1.y * w1 + v2.y * w2 + v3.y * w3;
        }
        for (; u < m; ++u) {
            int s = __shfl(sv, u);
            float w = __shfl(wv, u);
            float2 v = hW2[(size_t)s * 64 + lane];
            accx += v.x * w; accy += v.y * w;
        }
    }
    float di = dis[i];
    float2 hv = hW2[(size_t)i * 64 + lane];
    float ox = fmaxf(di * accx + hv.x * (di * di) + bias[lane * 2], 0.f);
    float oy = fmaxf(di * accy + hv.y * (di * di) + bias[lane * 2 + 1], 0.f);
    float2 o; o.x = ox; o.y = oy;
    ((float2*)hout)[(size_t)i * 64 + lane] = o;
    float part = ox * Wsc[lane * 2] + oy * Wsc[lane * 2 + 1];
    #pragma unroll
    for (int sh = 32; sh >= 1; sh >>= 1) part += __shfl_xor(part, sh);
    if (lane == 0) { hs[i] = part; hsd[i] = part * di; }
}

// ---- fused: score gather + per-graph top-k + newid + pool(tanh gate) + readout ----
// One block per graph, blockDim = CAP.
template <int CAP, int K>
__global__ void score_topk_pool_k(const float* __restrict__ hout,
                                  const float* __restrict__ hs, const float* __restrict__ hsd,
                                  const int* __restrict__ csr_src, const int* __restrict__ off,
                                  const int* __restrict__ cnt, const float* __restrict__ dis,
                                  const float* __restrict__ bs,
                                  float* __restrict__ hA, float* __restrict__ z,
                                  int* __restrict__ newid, int cur) {
    __shared__ float v[CAP];
    __shared__ int ix[CAP];
    __shared__ float zm[CAP];
    __shared__ float zs[CAP];
    int b = blockIdx.x, t = threadIdx.x;
    // 1) score (GCN with shared CSR/dis)
    float sc = -INFINITY;
    if (t < cur) {
        int i = b * cur + t;
        int s0 = off[i], e0 = s0 + cnt[i];
        float acc = 0.f;
        int j = s0;
        for (; j + 8 <= e0; j += 8) {
            int sx[8];
            #pragma unroll
            for (int u = 0; u < 8; ++u) sx[u] = csr_src[j + u];
            #pragma unroll
            for (int u = 0; u < 8; ++u) acc += hsd[sx[u]];
        }
        for (; j < e0; ++j) acc += hsd[csr_src[j]];
        float di = dis[i];
        sc = di * acc + hs[i] * (di * di) + bs[0];
    }
    v[t] = sc; ix[t] = t;
    __syncthreads();
    // 2) bitonic sort (value desc, idx asc)
    for (int size = 2; size <= CAP; size <<= 1) {
        for (int stride = size >> 1; stride > 0; stride >>= 1) {
            if (t < CAP / 2) {
                int pos = 2 * t - (t & (stride - 1));
                int j2 = pos + stride;
                bool asc = (pos & size) == 0;
                float v0 = v[pos], v1 = v[j2];
                int i0 = ix[pos], i1 = ix[j2];
                bool jb = (v1 > v0) || (v1 == v0 && i1 < i0);
                bool sw = asc ? jb : !jb;
                if (sw) { v[pos] = v1; v[j2] = v0; ix[pos] = i1; ix[j2] = i0; }
            }
            __syncthreads();
        }
    }
    // 3) newid for ALL of this graph's old nodes (selected -> new id, else -1)
    if (t < K)            newid[b * cur + ix[t]] = b * K + t;
    else if (ix[t] < cur) newid[b * cur + ix[t]] = -1;
    if (t < K) zm[t] = tanhf(v[t]);  // gates
    __syncthreads();
    // 4) pool gather + readout (max/mean over selected rows)
    if constexpr (CAP >= 128) {
        const int G = CAP / 128;
        int g = t >> 7, f = t & 127;
        float vmax = -INFINITY, vsum = 0.f;
        for (int j = g; j < K; j += G) {
            int src = b * cur + ix[j];
            float val = hout[(size_t)src * 128 + f] * zm[j];
            hA[((size_t)b * K + j) * 128 + f] = val;
            vmax = fmaxf(vmax, val); vsum += val;
        }
        __syncthreads();
        zm[t] = vmax; zs[t] = vsum;
        __syncthreads();
        if (t < 128) {
            float m = zm[t], s2 = zs[t];
            for (int g2 = 1; g2 < G; ++g2) { m = fmaxf(m, zm[g2 * 128 + t]); s2 += zs[g2 * 128 + t]; }
            z[b * 256 + t] += m;
            z[b * 256 + 128 + t] += s2 / (float)K;
        }
    } else {
        // CAP == 64: two features per thread
        float vmax0 = -INFINITY, vsum0 = 0.f, vmax1 = -INFINITY, vsum1 = 0.f;
        for (int j = 0; j < K; ++j) {
            int src = b * cur + ix[j];
            float gt = zm[j];
            float a = hout[(size_t)src * 128 + t] * gt;
            float c = hout[(size_t)src * 128 + 64 + t] * gt;
            hA[((size_t)b * K + j) * 128 + t] = a;
            hA[((size_t)b * K + j) * 128 + 64 + t] = c;
            vmax0 = fmaxf(vmax0, a); vsum0 += a;
            vmax1 = fmaxf(vmax1, c); vsum1 += c;
        }
        z[b * 256 + t] += vmax0;
        z[b * 256 + 64 + t] += vmax1;
        z[b * 256 + 128 + t] += vsum0 / (float)K;
        z[b * 256 + 192 + t] += vsum1 / (float)K;
    }
}

// ---------------- MLP head + log_softmax ----------------
__global__ void mlp_head_k(const float* __restrict__ z,
                           const float* __restrict__ Wl1, const float* __restrict__ bl1,
                           const float* __restrict__ Wl2, const float* __restrict__ bl2,
                           const float* __restrict__ Wl3, const float* __restrict__ bl3,
                           float* __restrict__ out) {
    __shared__ float zr[256], h1[128], h2[64], lg[NCLS], red[2];
    int b = blockIdx.x, t = threadIdx.x;  // 128 threads
    zr[t] = z[b * 256 + t];
    zr[t + 128] = z[b * 256 + 128 + t];
    __syncthreads();
    float acc = bl1[t];
    #pragma unroll 8
    for (int i = 0; i < 256; ++i) acc += zr[i] * Wl1[i * 128 + t];
    h1[t] = fmaxf(acc, 0.f);
    __syncthreads();
    if (t < 64) {
        float a2 = bl2[t];
        #pragma unroll 8
        for (int i = 0; i < 128; ++i) a2 += h1[i] * Wl2[i * 64 + t];
        h2[t] = fmaxf(a2, 0.f);
    }
    __syncthreads();
    if (t < NCLS) {
        float a3 = bl3[t];
        #pragma unroll 8
        for (int i = 0; i < 64; ++i) a3 += h2[i] * Wl3[i * NCLS + t];
        lg[t] = a3;
    }
    __syncthreads();
    if (t == 0) {
        float m = lg[0];
        for (int i = 1; i < NCLS; ++i) m = fmaxf(m, lg[i]);
        float s = 0.f;
        for (int i = 0; i < NCLS; ++i) s += expf(lg[i] - m);
        red[0] = m; red[1] = logf(s);
    }
    __syncthreads();
    if (t < NCLS) out[b * NCLS + t] = lg[t] - red[0] - red[1];
}

// ---------------- host ----------------
extern "C" void kernel_launch(void* const* d_in, const int* in_sizes, int n_in,
                              void* d_out, int out_size, void* d_ws, size_t ws_size,
                              hipStream_t stream) {
    const float* x   = (const float*)d_in[0];
    const int*   ei  = (const int*)d_in[1];
    const float* W1  = (const float*)d_in[2];  const float* b1  = (const float*)d_in[3];
    const float* W2  = (const float*)d_in[4];  const float* b2  = (const float*)d_in[5];
    const float* W3  = (const float*)d_in[6];  const float* b3  = (const float*)d_in[7];
    const float* Ws1 = (const float*)d_in[8];  const float* bs1 = (const float*)d_in[9];
    const float* Ws2 = (const float*)d_in[10]; const float* bs2 = (const float*)d_in[11];
    const float* Ws3 = (const float*)d_in[12]; const float* bs3 = (const float*)d_in[13];
    const float* Wl1 = (const float*)d_in[14]; const float* bl1 = (const float*)d_in[15];
    const float* Wl2 = (const float*)d_in[16]; const float* bl2 = (const float*)d_in[17];
    const float* Wl3 = (const float*)d_in[18]; const float* bl3 = (const float*)d_in[19];
    float* out = (float*)d_out;

    const int NMAX = NB * N0;  // 65536

    char* p = (char*)d_ws;
    // --- zeroed-once region (single memset): cnt0, cnt1, cnt2, gctr, z ---
    int*   cnt0 = (int*)p;   p += (size_t)NMAX * 4;
    int*   cnt1 = (int*)p;   p += (size_t)NB * KP1 * 4;
    int*   cnt2 = (int*)p;   p += (size_t)NB * KP2 * 4;
    int*   gctr = (int*)p;   p += 4 * 4;
    float* z    = (float*)p; p += (size_t)NB * 256 * 4;
    size_t zero_bytes = (size_t)(p - (char*)d_ws);
    // --- rest ---
    float* hW     = (float*)p; p += (size_t)NMAX * 128 * 4;
    float* hout   = (float*)p; p += (size_t)NMAX * 128 * 4;
    float* hA     = (float*)p; p += (size_t)NB * KP1 * 128 * 4;
    float* dis    = (float*)p; p += (size_t)NMAX * 4;
    float* hs     = (float*)p; p += (size_t)NMAX * 4;
    float* hsd    = (float*)p; p += (size_t)NMAX * 4;
    int* newid    = (int*)p;   p += (size_t)NMAX * 4;
    int* off      = (int*)p;   p += (size_t)NMAX * 4;
    int* cursor   = (int*)p;   p += (size_t)NMAX * 4;
    int2* ebuf    = (int2*)p;  p += (size_t)NEDGE * 8;
    int* csr_src  = (int*)p;   p += (size_t)NEDGE * 4;

    const int EB = ceil_div(NEDGE, 256);

    hipMemsetAsync(d_ws, 0, zero_bytes, stream);
    init_edges_count_k<<<EB, 256, 0, stream>>>(ei, ebuf, cnt0);

    auto stage = [&](const float* Ain, int HI, int cur, int sidx,
                     int* cntC, int* cntN,
                     const float* W, const float* bb,
                     const float* Wsc, const float* bsc) {
        int n = cur * NB;
        if (HI == FIN) {
            gemm_fin_k<<<n / 4, 256, 0, stream>>>(Ain, W, hW, n);
        } else {
            dim3 g(ceil_div(n, 64), 2);
            gemm128_tiled_k<<<g, 256, 0, stream>>>(Ain, W, hW, n);
        }
        offsets_k<<<ceil_div(n, 256), 256, 0, stream>>>(cntC, off, cursor, dis, gctr + sidx, n);
        scatter_k<<<EB, 256, 0, stream>>>(ebuf, cursor, csr_src);
        // n/4 blocks, divisible by 8 for all stages (16384 / 3280 / 656)
        gcn_agg_fused2_k<<<n / 4, 256, 0, stream>>>(
            hW, csr_src, off, cntC, dis, bb, Wsc, hout, hs, hsd, n, n / 32);
        if (cur == N0)
            score_topk_pool_k<1024, KP1><<<NB, 1024, 0, stream>>>(
                hout, hs, hsd, csr_src, off, cntC, dis, bsc, hA, z, newid, cur);
        else if (cur == KP1)
            score_topk_pool_k<256, KP2><<<NB, 256, 0, stream>>>(
                hout, hs, hsd, csr_src, off, cntC, dis, bsc, hA, z, newid, cur);
        else
            score_topk_pool_k<64, KP3><<<NB, 64, 0, stream>>>(
                hout, hs, hsd, csr_src, off, cntC, dis, bsc, hA, z, newid, cur);
        if (cntN)
            edge_update_count_k<<<EB, 256, 0, stream>>>(ebuf, newid, cntN);
    };

    stage(x,  FIN, N0,  0, cnt0, cnt1, W1, b1, Ws1, bs1);
    stage(hA, 128, KP1, 1, cnt1, cnt2, W2, b2, Ws2, bs2);
    stage(hA, 128, KP2, 2, cnt2, nullptr, W3, b3, Ws3, bs3);

    mlp_head_k<<<NB, 128, 0, stream>>>(z, Wl1, bl1, Wl2, bl2, Wl3, bl3, out);
}